// Round 13
// baseline (119.825 us; speedup 1.0000x reference)
//
#include <hip/hip_runtime.h>
#include <hip/hip_bf16.h>
#include <math.h>

typedef __attribute__((ext_vector_type(8))) short short8;
typedef __attribute__((ext_vector_type(4))) float f32x4;
typedef __attribute__((ext_vector_type(4))) unsigned int u32x4;

#define NB   128   // batch
#define TT   64    // timesteps (T-1)
#define DD   512   // feature dim
#define HH   128   // hidden dim
#define WVD  128   // wordvec dim
#define VV   10000 // vocab
#define VP   10048 // vocab padded to multiple of 64
#define NROW (NB*TT)
#define NTILE (VP/64)    // 157 column tiles of 64
#define VT   32          // col-tile streams (blocks per row-block)
#define TILE_BYTES 16384 // 64 cols x 128 k x 2 B
#define LOG2E 1.44269504088896f
#define LN2   0.69314718055995f

__device__ __forceinline__ unsigned short f2bf(float x) {
  union { float f; unsigned int u; } v; v.f = x;
  unsigned int r = v.u + 0x7fffu + ((v.u >> 16) & 1u);
  return (unsigned short)(r >> 16);
}
__device__ __forceinline__ float bf2f(unsigned short u) {
  union { unsigned int i; float f; } v; v.i = ((unsigned int)u) << 16; return v.f;
}
__device__ __forceinline__ short8 cvt2bf8(f32x4 a, f32x4 b) {
  short8 t;
  t[0]=(short)f2bf(a[0]); t[1]=(short)f2bf(a[1]);
  t[2]=(short)f2bf(a[2]); t[3]=(short)f2bf(a[3]);
  t[4]=(short)f2bf(b[0]); t[5]=(short)f2bf(b[1]);
  t[6]=(short)f2bf(b[2]); t[7]=(short)f2bf(b[3]);
  return t;
}
// packed f32 pair -> 2x bf16 in one u32 (RNE), single HW instr on gfx950
__device__ __forceinline__ unsigned int cvtpk(float lo, float hi) {
  unsigned int r;
  asm("v_cvt_pk_bf16_f32 %0, %1, %2" : "=v"(r) : "v"(lo), "v"(hi));
  return r;
}

// LDS-only barrier: lgkmcnt(0) + raw s_barrier; vmcnt stays in flight.
__device__ __forceinline__ void lds_barrier() {
  asm volatile("s_waitcnt lgkmcnt(0)" ::: "memory");
  __builtin_amdgcn_s_barrier();
  asm volatile("" ::: "memory");
  __builtin_amdgcn_sched_barrier(0);
}

// ---------------------------------------------------------------------------
// K_setup: h0 + xbt (everything the RNN needs before it can start).
//   [0,128)   : h0[n] = features[n] @ W_proj + b_proj (VALU GEMV)
//   [128,160) : xbt = gather(embed) @ W_ih^T + b_ih + b_hh via MFMA,
//               scattered into the k_rnn fragment layout:
//               off = (g*512 + t*8 + ct)*256 + (l4r*16+lc)*4 + jjr
// ---------------------------------------------------------------------------
__global__ __launch_bounds__(256) void k_setup(
    const float* __restrict__ features, const float* __restrict__ Wp,
    const float* __restrict__ bp, float* __restrict__ h0,
    const int* __restrict__ captions, const float* __restrict__ embed,
    const float* __restrict__ Wih, const float* __restrict__ bih,
    const float* __restrict__ bhh, float* __restrict__ xbt) {
  __shared__ __align__(16) char smem[32768];
  int b = blockIdx.x, tid = threadIdx.x;

  if (b < 128) {
    int n = b;
    float* fl  = (float*)smem;
    f32x4* red = (f32x4*)(smem + 2048);
    fl[tid]       = features[n*DD + tid];
    fl[tid + 256] = features[n*DD + 256 + tid];
    __syncthreads();
    int jq = (tid & 31) * 4;
    int ks = tid >> 5;
    f32x4 acc = {0.f,0.f,0.f,0.f};
    const float* wp = Wp + (size_t)(ks*64)*HH + jq;
    #pragma unroll 4
    for (int k = 0; k < 64; ++k) {
      f32x4 wv = *(const f32x4*)(wp + (size_t)k*HH);
      acc += fl[ks*64 + k] * wv;
    }
    red[ks*32 + (tid & 31)] = acc;
    __syncthreads();
    if (tid < 32) {
      f32x4 s = red[tid];
      #pragma unroll
      for (int i = 1; i < 8; ++i) s += red[i*32 + tid];
      s += *(const f32x4*)(bp + tid*4);
      *(f32x4*)(h0 + n*HH + tid*4) = s;
    }
  } else {
    // ---- xbt GEMM, scattered into k_rnn fragment layout ----
    char* wihbf = smem;   // 32 KB swizzled bf16 Wih
    int w = tid >> 6, l = tid & 63;
    int l4 = l >> 4, lc = l & 15;
    {
      int row = tid >> 1, half = tid & 1;
      const float* src = Wih + (size_t)row*WVD + half*64;
      #pragma unroll
      for (int i = 0; i < 8; ++i) {
        f32x4 a = *(const f32x4*)(src + i*8);
        f32x4 c = *(const f32x4*)(src + i*8 + 4);
        int chunk = half*8 + i;
        *(short8*)(wihbf + row*256 + ((chunk << 4) ^ ((row & 7) << 4))) = cvt2bf8(a, c);
      }
    }
    int bp2 = b - 128;
    int nn = bp2*4 + w;                 // sample (fixed per wave)
    int g = nn >> 4;
    int sr = nn & 15;
    int l4r = sr >> 2, jjr = sr & 3;
    int lanebase = (l4r*16 + lc)*4 + jjr;
    short8 af[4][4];
    #pragma unroll
    for (int sm = 0; sm < 4; ++sm) {
      int t = sm*16 + lc;
      const float* x = embed + (size_t)captions[nn*65 + t] * WVD;
      #pragma unroll
      for (int ks = 0; ks < 4; ++ks) {
        const float* p = x + ks*32 + l4*8;
        af[sm][ks] = cvt2bf8(*(const f32x4*)p, *(const f32x4*)(p+4));
      }
    }
    __syncthreads();
    #pragma unroll
    for (int ct = 0; ct < 8; ++ct) {
      int rowb = ct*16 + lc;
      short8 bf[4];
      #pragma unroll
      for (int ks = 0; ks < 4; ++ks)
        bf[ks] = *(const short8*)(wihbf + rowb*256 + (((ks*4 + l4) << 4) ^ ((rowb & 7) << 4)));
      int col = ct*16 + lc;
      float bb = bih[col] + bhh[col];
      #pragma unroll
      for (int sm = 0; sm < 4; ++sm) {
        f32x4 acc = {0.f,0.f,0.f,0.f};
        #pragma unroll
        for (int ks = 0; ks < 4; ++ks)
          acc = __builtin_amdgcn_mfma_f32_16x16x32_bf16(af[sm][ks], bf[ks], acc, 0, 0, 0);
        #pragma unroll
        for (int jj = 0; jj < 4; ++jj) {
          int t = sm*16 + l4*4 + jj;
          xbt[(size_t)(g*512 + t*8 + ct)*256 + lanebase] = acc[jj] + bb;
        }
      }
    }
  }
}

// ---------------------------------------------------------------------------
// K_rnnt: fused RNN + W_vocab transpose + expbv + out-zero.
//   [0,4)     : MFMA recurrence, TWO independent 16-sample groups per block
//               interleaved in one instruction stream (latency of group0's
//               ds_read/trans hidden under group1's MFMA/epilogue). One
//               lgkm-only barrier per step; vmcnt never drained in-loop.
//   [4,318)   : Wvt[v][k] = bf16(W_vocab[k][v] * LOG2E) (tile transpose)
//   [318,358) : expbv[v] = exp(b_vocab[v]) (0 for pad)
//   358       : out = 0
// ---------------------------------------------------------------------------
__global__ __launch_bounds__(256, 1) void k_rnnt(
    const float* __restrict__ h0, const float* __restrict__ xbt,
    const float* __restrict__ Whh, unsigned short* __restrict__ hsb,
    const float* __restrict__ Wv, unsigned short* __restrict__ Wvt,
    const float* __restrict__ bv, float* __restrict__ expbv,
    float* __restrict__ out) {
  __shared__ __align__(16) char smem[16640];
  int b = blockIdx.x, tid = threadIdx.x;

  if (b >= 4) {
    if (b < 318) {
      // ---- W_vocab transpose tile (fold LOG2E) ----
      float (*tile)[65] = (float (*)[65])smem;
      int tb = b - 4;
      int bvv = (tb >> 1) * 64;
      int bk  = (tb & 1) * 64;
      int tv = tid & 63;
      int tk0 = tid >> 6;
      #pragma unroll
      for (int kk = 0; kk < 64; kk += 4) {
        int k = bk + kk + tk0;
        int v = bvv + tv;
        tile[kk + tk0][tv] = (v < VV) ? Wv[(size_t)k*VV + v] : 0.f;
      }
      __syncthreads();
      int tk = tid & 63;
      int tv0 = tid >> 6;
      #pragma unroll
      for (int vv = 0; vv < 64; vv += 4) {
        int v = bvv + vv + tv0;
        Wvt[(size_t)v*HH + bk + tk] = f2bf(tile[tk][vv + tv0] * LOG2E);
      }
    } else if (b < 358) {
      int v = (b - 318)*256 + tid;
      if (v < VP) expbv[v] = (v < VV) ? __expf(bv[v]) : 0.f;
    } else {
      if (tid == 0) out[0] = 0.f;
    }
    return;
  }

  // ================== RNN: block b, groups {2b, 2b+1} ======================
  int n0 = b * 32;                       // 32 samples per block
  int w = tid >> 6, l = tid & 63;
  int l4 = l >> 4, lc = l & 15;

  // persistent Whh B-fragments (shared by both groups)
  short8 bw[2][4];
  int jcol[2];
  #pragma unroll
  for (int c = 0; c < 2; ++c) {
    int jc = (2*w + c)*16 + lc;
    jcol[c] = jc;
    #pragma unroll
    for (int ks = 0; ks < 4; ++ks) {
      const float* p = Whh + (size_t)jc*HH + ks*32 + l4*8;
      bw[c][ks] = cvt2bf8(*(const f32x4*)p, *(const f32x4*)(p+4));
    }
  }

  // H[0] <- h0 for both groups (bf16, swizzled). g0 @ 0, g1 @ 8192.
  {
    int s = tid >> 4, ch = tid & 15;
    int wofs = s*256 + ((ch*16) ^ ((s&7)<<4));
    const float* p0 = h0 + (size_t)(n0 + s)*HH + ch*8;
    *(short8*)(smem + wofs) = cvt2bf8(*(const f32x4*)p0, *(const f32x4*)(p0+4));
    const float* p1 = h0 + (size_t)(n0 + 16 + s)*HH + ch*8;
    *(short8*)(smem + 8192 + wofs) = cvt2bf8(*(const f32x4*)p1, *(const f32x4*)(p1+4));
  }

  // loop-invariant LDS addresses (per group, per buffer)
  const char *rd0_0[4], *rd0_1[4], *rd1_0[4], *rd1_1[4];
  #pragma unroll
  for (int ks = 0; ks < 4; ++ks) {
    int off = lc*256 + ((ks*64 + l4*16) ^ ((lc&7)<<4));
    rd0_0[ks] = smem + off;          rd0_1[ks] = smem + 4096 + off;
    rd1_0[ks] = smem + 8192 + off;   rd1_1[ks] = smem + 12288 + off;
  }
  char *wr0_0[8], *wr0_1[8], *wr1_0[8], *wr1_1[8]; // wrX_B used when reading buf B
  #pragma unroll
  for (int c = 0; c < 2; ++c)
    #pragma unroll
    for (int jj = 0; jj < 4; ++jj) {
      int s = l4*4 + jj;
      int off = s*256 + ((jcol[c]*2) ^ ((s&7)<<4));
      wr0_0[c*4+jj] = smem + 4096 + off;   wr0_1[c*4+jj] = smem + off;
      wr1_0[c*4+jj] = smem + 12288 + off;  wr1_1[c*4+jj] = smem + 8192 + off;
    }
  int fs = tid >> 4, fo = (tid & 15) * 16;
  int fofs = fs*256 + (fo ^ ((fs&7)<<4));
  const char *fr0_0 = smem + fofs,         *fr0_1 = smem + 4096 + fofs;
  const char *fr1_0 = smem + 8192 + fofs,  *fr1_1 = smem + 12288 + fofs;
  unsigned short* hst0 = hsb + (size_t)(n0 + fs)*TT*HH + (fo >> 1) - HH;
  unsigned short* hst1 = hsb + (size_t)(n0 + 16 + fs)*TT*HH + (fo >> 1) - HH;

  // x prefetch: fragment-ordered xbt, per group, per t-parity; depth 2
  const float *xp0_0 = xbt + ((size_t)(2*b)*512 + w*2)*256 + l*4;
  const float *xp0_1 = xp0_0 + 2048;
  const float *xp1_0 = xbt + ((size_t)(2*b+1)*512 + w*2)*256 + l*4;
  const float *xp1_1 = xp1_0 + 2048;
  f32x4 xr0_0_0 = *xp0_0, xr0_0_1 = *(xp0_0 + 256); xp0_0 += 4096;
  f32x4 xr0_1_0 = *xp0_1, xr0_1_1 = *(xp0_1 + 256); xp0_1 += 4096;
  f32x4 xr1_0_0 = *xp1_0, xr1_0_1 = *(xp1_0 + 256); xp1_0 += 4096;
  f32x4 xr1_1_0 = *xp1_1, xr1_1_1 = *(xp1_1 + 256); xp1_1 += 4096;

  lds_barrier();   // H[0] visible (vmcnt prefetches stay in flight)

#define MFMA16(a,b_,c) __builtin_amdgcn_mfma_f32_16x16x32_bf16(a,b_,c,0,0,0)
#define BODY(GI, BUF, DOSTORE) do {                                           \
    short8 ah0 = *(const short8*)rd##GI##_##BUF[0];                           \
    short8 ah1 = *(const short8*)rd##GI##_##BUF[1];                           \
    short8 ah2 = *(const short8*)rd##GI##_##BUF[2];                           \
    short8 ah3 = *(const short8*)rd##GI##_##BUF[3];                           \
    f32x4 xn0 = *(const f32x4*)xp##GI##_##BUF;                                \
    f32x4 xn1 = *(const f32x4*)(xp##GI##_##BUF + 256);                        \
    xp##GI##_##BUF += 4096;                                                   \
    if (DOSTORE) { u32x4 fv = *(const u32x4*)fr##GI##_##BUF;                  \
                   *(u32x4*)hst##GI = fv; }                                   \
    hst##GI += HH;                                                            \
    f32x4 aA0={0.f,0.f,0.f,0.f}, aA1={0.f,0.f,0.f,0.f};                       \
    f32x4 aB0={0.f,0.f,0.f,0.f}, aB1={0.f,0.f,0.f,0.f};                       \
    aA0 = MFMA16(ah0, bw[0][0], aA0); aA1 = MFMA16(ah0, bw[1][0], aA1);       \
    aB0 = MFMA16(ah2, bw[0][2], aB0); aB1 = MFMA16(ah2, bw[1][2], aB1);       \
    aA0 = MFMA16(ah1, bw[0][1], aA0); aA1 = MFMA16(ah1, bw[1][1], aA1);       \
    aB0 = MFMA16(ah3, bw[0][3], aB0); aB1 = MFMA16(ah3, bw[1][3], aB1);       \
    float hv0[4], hv1[4];                                                     \
    _Pragma("unroll")                                                         \
    for (int jj = 0; jj < 4; ++jj) {                                          \
      float v0 = aA0[jj] + aB0[jj] + xr##GI##_##BUF##_0[jj];                  \
      float e0 = __builtin_amdgcn_exp2f(v0 * (2.0f*LOG2E));                   \
      hv0[jj] = fmaf(-2.0f, __builtin_amdgcn_rcpf(e0 + 1.0f), 1.0f);          \
      float v1 = aA1[jj] + aB1[jj] + xr##GI##_##BUF##_1[jj];                  \
      float e1 = __builtin_amdgcn_exp2f(v1 * (2.0f*LOG2E));                   \
      hv1[jj] = fmaf(-2.0f, __builtin_amdgcn_rcpf(e1 + 1.0f), 1.0f);          \
    }                                                                         \
    xr##GI##_##BUF##_0 = xn0; xr##GI##_##BUF##_1 = xn1;                       \
    unsigned int p01 = cvtpk(hv0[0], hv0[1]), p23 = cvtpk(hv0[2], hv0[3]);    \
    unsigned int q01 = cvtpk(hv1[0], hv1[1]), q23 = cvtpk(hv1[2], hv1[3]);    \
    *(unsigned short*)wr##GI##_##BUF[0] = (unsigned short)p01;                \
    *(unsigned short*)wr##GI##_##BUF[1] = (unsigned short)(p01 >> 16);        \
    *(unsigned short*)wr##GI##_##BUF[2] = (unsigned short)p23;                \
    *(unsigned short*)wr##GI##_##BUF[3] = (unsigned short)(p23 >> 16);        \
    *(unsigned short*)wr##GI##_##BUF[4] = (unsigned short)q01;                \
    *(unsigned short*)wr##GI##_##BUF[5] = (unsigned short)(q01 >> 16);        \
    *(unsigned short*)wr##GI##_##BUF[6] = (unsigned short)q23;                \
    *(unsigned short*)wr##GI##_##BUF[7] = (unsigned short)(q23 >> 16);        \
  } while (0)

  BODY(0, 0, 0); BODY(1, 0, 0); lds_barrier();   // t = 0 (no hsb store yet)
  BODY(0, 1, 1); BODY(1, 1, 1); lds_barrier();   // t = 1
  #pragma unroll 1
  for (int it = 1; it < 32; ++it) {
    BODY(0, 0, 1); BODY(1, 0, 1); lds_barrier();
    BODY(0, 1, 1); BODY(1, 1, 1); lds_barrier();
  }
  // final flush: buf0 holds h_64 -> row 63
  { u32x4 fv = *(const u32x4*)fr0_0; *(u32x4*)hst0 = fv; }
  { u32x4 fv = *(const u32x4*)fr1_0; *(u32x4*)hst1 = fv; }
#undef BODY
#undef MFMA16
}

// ---------------------------------------------------------------------------
// K_loss: sum-exp of scores via LDS-staged B, 2-phase pipeline. (unchanged)
// ---------------------------------------------------------------------------
__global__ __launch_bounds__(256) void k_loss(
    const unsigned short* __restrict__ hsb,
    const unsigned short* __restrict__ wvt,
    const float* __restrict__ expbv,
    float* __restrict__ se_part) {
  __shared__ unsigned short bt[2][TILE_BYTES/2];   // 2 x 16 KB
  int tid = threadIdx.x;
  int w = tid >> 6, l = tid & 63;
  int l4 = l >> 4, lc = l & 15;
  int rb = blockIdx.x >> 5;
  int vt = blockIdx.x & 31;
  int wrow = rb*256 + w*64;

  short8 af[4][4];
  #pragma unroll
  for (int sm = 0; sm < 4; ++sm)
    #pragma unroll
    for (int ks = 0; ks < 4; ++ks)
      af[sm][ks] = *(const short8*)(hsb + (size_t)(wrow + sm*16 + lc)*HH + ks*32 + l4*8);

  int T = (lc & 7) << 4;
  int sb[4];
  #pragma unroll
  for (int ks = 0; ks < 4; ++ks) sb[ks] = ((ks*64) + l4*16) ^ T;

#define STAGE(bufi, ct) do {                                                  \
    const char* _gb = (const char*)wvt + (size_t)(ct)*TILE_BYTES;             \
    _Pragma("unroll")                                                         \
    for (int q = 0; q < 4; ++q) {                                             \
      int _off = w*4096 + q*1024 + l*16;                                      \
      int _src = _off ^ (((_off >> 8) & 7) << 4);                             \
      __builtin_amdgcn_global_load_lds(                                       \
        (const __attribute__((address_space(1))) void*)(_gb + _src),          \
        (__attribute__((address_space(3))) void*)((char*)&bt[bufi][0] + w*4096 + q*1024), \
        16, 0, 0);                                                            \
    }                                                                         \
  } while (0)

#define EBLOAD(dst, ct) do {                                                  \
    const float* _e = expbv + (ct)*64 + lc;                                   \
    dst[0] = _e[0]; dst[1] = _e[16]; dst[2] = _e[32]; dst[3] = _e[48];        \
  } while (0)

#define COMPUTE(bufi, ebv_) do {                                              \
    const char* _Bb = (const char*)&bt[bufi][0];                              \
    _Pragma("unroll")                                                         \
    for (int st = 0; st < 4; ++st) {                                          \
      const char* _Bs = _Bb + st*4096 + lc*256;                               \
      short8 _b0 = *(const short8*)(_Bs + sb[0]);                             \
      short8 _b1 = *(const short8*)(_Bs + sb[1]);                             \
      short8 _b2 = *(const short8*)(_Bs + sb[2]);                             \
      short8 _b3 = *(const short8*)(_Bs + sb[3]);                             \
      float _eb = ebv_[st];                                                   \
      _Pragma("unroll")                                                       \
      for (int sm = 0; sm < 4; ++sm) {                                        \
        f32x4 _acc = {0.f,0.f,0.f,0.f};                                       \
        _acc = __builtin_amdgcn_mfma_f32_16x16x32_bf16(af[sm][0], _b0, _acc, 0,0,0); \
        _acc = __builtin_amdgcn_mfma_f32_16x16x32_bf16(af[sm][1], _b1, _acc, 0,0,0); \
        _acc = __builtin_amdgcn_mfma_f32_16x16x32_bf16(af[sm][2], _b2, _acc, 0,0,0); \
        _acc = __builtin_amdgcn_mfma_f32_16x16x32_bf16(af[sm][3], _b3, _acc, 0,0,0); \
        _Pragma("unroll")                                                     \
        for (int jj = 0; jj < 4; ++jj)                                        \
          se[sm][jj] = fmaf(__builtin_amdgcn_exp2f(_acc[jj]), _eb, se[sm][jj]); \
      }                                                                       \
    }                                                                         \
  } while (0)

  float se[4][4] = {{0.f}};
  float ebc[4], ebn[4];
  STAGE(0, vt);
  EBLOAD(ebc, vt);
  __syncthreads();
  int i = 0;
  for (;;) {
    int nextct = vt + (i+1)*VT;
    if (nextct < NTILE) { STAGE((i+1)&1, nextct); EBLOAD(ebn, nextct); }
    COMPUTE(i&1, ebc);
    if (nextct >= NTILE) break;
    __syncthreads();
    ebc[0]=ebn[0]; ebc[1]=ebn[1]; ebc[2]=ebn[2]; ebc[3]=ebn[3];
    ++i;
  }

  #pragma unroll
  for (int sm = 0; sm < 4; ++sm)
    #pragma unroll
    for (int jj = 0; jj < 4; ++jj) {
      float v = se[sm][jj];
      v += __shfl_xor(v, 1); v += __shfl_xor(v, 2);
      v += __shfl_xor(v, 4); v += __shfl_xor(v, 8);
      se[sm][jj] = v;
    }
  if (lc == 0) {
    #pragma unroll
    for (int sm = 0; sm < 4; ++sm)
      #pragma unroll
      for (int jj = 0; jj < 4; ++jj)
        se_part[(size_t)vt*NROW + wrow + sm*16 + l4*4 + jj] = se[sm][jj];
  }
#undef STAGE
#undef EBLOAD
#undef COMPUTE
}

// ---------------------------------------------------------------------------
// K_final: sum 32 partials per row + target score + masked NLL reduction.
// ---------------------------------------------------------------------------
__global__ __launch_bounds__(256) void k_final(
    const unsigned short* __restrict__ hsb,
    const unsigned short* __restrict__ wvt,
    const float* __restrict__ bv,
    const float* __restrict__ se_part,
    const int* __restrict__ captions,
    float* __restrict__ out) {
  int tid = threadIdx.x;
  int w = tid >> 6, l = tid & 63;
  int row = blockIdx.x*32 + w*8 + (l >> 3);
  int seg = l & 7;
  int n = row >> 6, t = row & 63;
  int tg = captions[n*65 + t + 1];
  float sep = 0.f;
  #pragma unroll
  for (int i = 0; i < 4; ++i)
    sep += se_part[(size_t)(seg*4 + i)*NROW + row];
  float part = 0.f;
  if (tg != 0) {
    const unsigned short* a = hsb + (size_t)row*HH + seg*16;
    const unsigned short* bq = wvt + (size_t)tg*HH + seg*16;
    short8 a0 = *(const short8*)a, a1 = *(const short8*)(a+8);
    short8 b0 = *(const short8*)bq, b1 = *(const short8*)(bq+8);
    #pragma unroll
    for (int i = 0; i < 8; ++i) {
      part += bf2f((unsigned short)a0[i]) * bf2f((unsigned short)b0[i]);
      part += bf2f((unsigned short)a1[i]) * bf2f((unsigned short)b1[i]);
    }
  }
  part += __shfl_xor(part, 1); sep += __shfl_xor(sep, 1);
  part += __shfl_xor(part, 2); sep += __shfl_xor(sep, 2);
  part += __shfl_xor(part, 4); sep += __shfl_xor(sep, 4);
  if (seg == 0 && tg != 0) {
    float score = part * LN2 + bv[tg];
    float nll = logf(sep) - score;
    atomicAdd(out, nll * (1.0f/128.0f));
  }
}

extern "C" void kernel_launch(void* const* d_in, const int* in_sizes, int n_in,
                              void* d_out, int out_size, void* d_ws, size_t ws_size,
                              hipStream_t stream) {
  const float* features = (const float*)d_in[0];
  const int*   captions = (const int*)d_in[1];
  const float* W_proj   = (const float*)d_in[2];
  const float* b_proj   = (const float*)d_in[3];
  const float* embed    = (const float*)d_in[4];
  const float* W_ih     = (const float*)d_in[5];
  const float* W_hh     = (const float*)d_in[6];
  const float* b_ih     = (const float*)d_in[7];
  const float* b_hh     = (const float*)d_in[8];
  const float* W_vocab  = (const float*)d_in[9];
  const float* b_vocab  = (const float*)d_in[10];
  float* out = (float*)d_out;
  char* ws = (char*)d_ws;

  float*          h0      = (float*)(ws + 0x000000);            // 64 KB
  float*          se_part = (float*)(ws + 0x010000);            // 1 MB
  unsigned short* hsb     = (unsigned short*)(ws + 0x410000);   // 2 MB
  unsigned short* wvt     = (unsigned short*)(ws + 0x620000);   // 2.57 MB
  float*          expbv   = (float*)(ws + 0x8A0000);            // 40 KB
  float*          xbt     = (float*)(ws + 0x8B0000);            // 4 MB (+slack)

  hipLaunchKernelGGL(k_setup, dim3(160), dim3(256), 0, stream,
                     features, W_proj, b_proj, h0,
                     captions, embed, W_ih, b_ih, b_hh, xbt);
  hipLaunchKernelGGL(k_rnnt, dim3(359), dim3(256), 0, stream,
                     h0, xbt, W_hh, hsb,
                     W_vocab, wvt, b_vocab, expbv, out);
  hipLaunchKernelGGL(k_loss, dim3(32*VT), dim3(256), 0, stream,
                     hsb, wvt, expbv, se_part);
  hipLaunchKernelGGL(k_final, dim3(NROW/32), dim3(256), 0, stream,
                     hsb, wvt, b_vocab, se_part, captions, out);
}

// Round 14
// 119.096 us; speedup vs baseline: 1.0061x; 1.0061x over previous
//
#include <hip/hip_runtime.h>
#include <hip/hip_bf16.h>
#include <math.h>

typedef __attribute__((ext_vector_type(8))) short short8;
typedef __attribute__((ext_vector_type(4))) float f32x4;
typedef __attribute__((ext_vector_type(4))) unsigned int u32x4;

#define NB   128   // batch
#define TT   64    // timesteps (T-1)
#define DD   512   // feature dim
#define HH   128   // hidden dim
#define WVD  128   // wordvec dim
#define VV   10000 // vocab
#define VP   10048 // vocab padded to multiple of 64
#define NROW (NB*TT)
#define NTILE (VP/64)    // 157 column tiles of 64
#define VT   32          // col-tile streams (blocks per row-block)
#define TILE_BYTES 16384 // 64 cols x 128 k x 2 B
#define LOG2E 1.44269504088896f
#define LN2   0.69314718055995f

__device__ __forceinline__ unsigned short f2bf(float x) {
  union { float f; unsigned int u; } v; v.f = x;
  unsigned int r = v.u + 0x7fffu + ((v.u >> 16) & 1u);
  return (unsigned short)(r >> 16);
}
__device__ __forceinline__ float bf2f(unsigned short u) {
  union { unsigned int i; float f; } v; v.i = ((unsigned int)u) << 16; return v.f;
}
__device__ __forceinline__ short8 cvt2bf8(f32x4 a, f32x4 b) {
  short8 t;
  t[0]=(short)f2bf(a[0]); t[1]=(short)f2bf(a[1]);
  t[2]=(short)f2bf(a[2]); t[3]=(short)f2bf(a[3]);
  t[4]=(short)f2bf(b[0]); t[5]=(short)f2bf(b[1]);
  t[6]=(short)f2bf(b[2]); t[7]=(short)f2bf(b[3]);
  return t;
}
// packed f32 pair -> 2x bf16 in one u32 (RNE), single HW instr on gfx950
__device__ __forceinline__ unsigned int cvtpk(float lo, float hi) {
  unsigned int r;
  asm("v_cvt_pk_bf16_f32 %0, %1, %2" : "=v"(r) : "v"(lo), "v"(hi));
  return r;
}

// LDS-only barrier: lgkmcnt(0) + raw s_barrier; vmcnt stays in flight.
__device__ __forceinline__ void lds_barrier() {
  asm volatile("s_waitcnt lgkmcnt(0)" ::: "memory");
  __builtin_amdgcn_s_barrier();
  asm volatile("" ::: "memory");
  __builtin_amdgcn_sched_barrier(0);
}

// ---------------------------------------------------------------------------
// K_setup: h0 + xbt (everything the RNN needs before it can start).
//   [0,128)   : h0[n] = features[n] @ W_proj + b_proj (VALU GEMV)
//   [128,160) : xbt = gather(embed) @ W_ih^T + b_ih + b_hh via MFMA,
//               scattered into the k_rnn fragment layout:
//               off = (g*512 + t*8 + ct)*256 + (l4r*16+lc)*4 + jjr
// ---------------------------------------------------------------------------
__global__ __launch_bounds__(256) void k_setup(
    const float* __restrict__ features, const float* __restrict__ Wp,
    const float* __restrict__ bp, float* __restrict__ h0,
    const int* __restrict__ captions, const float* __restrict__ embed,
    const float* __restrict__ Wih, const float* __restrict__ bih,
    const float* __restrict__ bhh, float* __restrict__ xbt) {
  __shared__ __align__(16) char smem[32768];
  int b = blockIdx.x, tid = threadIdx.x;

  if (b < 128) {
    int n = b;
    float* fl  = (float*)smem;
    f32x4* red = (f32x4*)(smem + 2048);
    fl[tid]       = features[n*DD + tid];
    fl[tid + 256] = features[n*DD + 256 + tid];
    __syncthreads();
    int jq = (tid & 31) * 4;
    int ks = tid >> 5;
    f32x4 acc = {0.f,0.f,0.f,0.f};
    const float* wp = Wp + (size_t)(ks*64)*HH + jq;
    #pragma unroll 4
    for (int k = 0; k < 64; ++k) {
      f32x4 wv = *(const f32x4*)(wp + (size_t)k*HH);
      acc += fl[ks*64 + k] * wv;
    }
    red[ks*32 + (tid & 31)] = acc;
    __syncthreads();
    if (tid < 32) {
      f32x4 s = red[tid];
      #pragma unroll
      for (int i = 1; i < 8; ++i) s += red[i*32 + tid];
      s += *(const f32x4*)(bp + tid*4);
      *(f32x4*)(h0 + n*HH + tid*4) = s;
    }
  } else {
    // ---- xbt GEMM, scattered into k_rnn fragment layout ----
    char* wihbf = smem;   // 32 KB swizzled bf16 Wih
    int w = tid >> 6, l = tid & 63;
    int l4 = l >> 4, lc = l & 15;
    {
      int row = tid >> 1, half = tid & 1;
      const float* src = Wih + (size_t)row*WVD + half*64;
      #pragma unroll
      for (int i = 0; i < 8; ++i) {
        f32x4 a = *(const f32x4*)(src + i*8);
        f32x4 c = *(const f32x4*)(src + i*8 + 4);
        int chunk = half*8 + i;
        *(short8*)(wihbf + row*256 + ((chunk << 4) ^ ((row & 7) << 4))) = cvt2bf8(a, c);
      }
    }
    int bp2 = b - 128;
    int nn = bp2*4 + w;                 // sample (fixed per wave)
    int g = nn >> 4;
    int sr = nn & 15;
    int l4r = sr >> 2, jjr = sr & 3;
    int lanebase = (l4r*16 + lc)*4 + jjr;
    short8 af[4][4];
    #pragma unroll
    for (int sm = 0; sm < 4; ++sm) {
      int t = sm*16 + lc;
      const float* x = embed + (size_t)captions[nn*65 + t] * WVD;
      #pragma unroll
      for (int ks = 0; ks < 4; ++ks) {
        const float* p = x + ks*32 + l4*8;
        af[sm][ks] = cvt2bf8(*(const f32x4*)p, *(const f32x4*)(p+4));
      }
    }
    __syncthreads();
    #pragma unroll
    for (int ct = 0; ct < 8; ++ct) {
      int rowb = ct*16 + lc;
      short8 bf[4];
      #pragma unroll
      for (int ks = 0; ks < 4; ++ks)
        bf[ks] = *(const short8*)(wihbf + rowb*256 + (((ks*4 + l4) << 4) ^ ((rowb & 7) << 4)));
      int col = ct*16 + lc;
      float bb = bih[col] + bhh[col];
      #pragma unroll
      for (int sm = 0; sm < 4; ++sm) {
        f32x4 acc = {0.f,0.f,0.f,0.f};
        #pragma unroll
        for (int ks = 0; ks < 4; ++ks)
          acc = __builtin_amdgcn_mfma_f32_16x16x32_bf16(af[sm][ks], bf[ks], acc, 0, 0, 0);
        #pragma unroll
        for (int jj = 0; jj < 4; ++jj) {
          int t = sm*16 + l4*4 + jj;
          xbt[(size_t)(g*512 + t*8 + ct)*256 + lanebase] = acc[jj] + bb;
        }
      }
    }
  }
}

// ---------------------------------------------------------------------------
// K_rnnt: fused RNN + W_vocab transpose + expbv + out-zero.
//   [0,4)     : MFMA recurrence, TWO independent 16-sample groups per block
//               interleaved in one instruction stream (latency of group0's
//               ds_read/trans hidden under group1's MFMA/epilogue). One
//               lgkm-only barrier per step; vmcnt never drained in-loop.
//   [4,318)   : Wvt[v][k] = bf16(W_vocab[k][v] * LOG2E) (tile transpose)
//   [318,358) : expbv[v] = exp(b_vocab[v]) (0 for pad)
//   358       : out = 0
// ---------------------------------------------------------------------------
__global__ __launch_bounds__(256, 1) void k_rnnt(
    const float* __restrict__ h0, const float* __restrict__ xbt,
    const float* __restrict__ Whh, unsigned short* __restrict__ hsb,
    const float* __restrict__ Wv, unsigned short* __restrict__ Wvt,
    const float* __restrict__ bv, float* __restrict__ expbv,
    float* __restrict__ out) {
  __shared__ __align__(16) char smem[16640];
  int b = blockIdx.x, tid = threadIdx.x;

  if (b >= 4) {
    if (b < 318) {
      // ---- W_vocab transpose tile (fold LOG2E) ----
      float (*tile)[65] = (float (*)[65])smem;
      int tb = b - 4;
      int bvv = (tb >> 1) * 64;
      int bk  = (tb & 1) * 64;
      int tv = tid & 63;
      int tk0 = tid >> 6;
      #pragma unroll
      for (int kk = 0; kk < 64; kk += 4) {
        int k = bk + kk + tk0;
        int v = bvv + tv;
        tile[kk + tk0][tv] = (v < VV) ? Wv[(size_t)k*VV + v] : 0.f;
      }
      __syncthreads();
      int tk = tid & 63;
      int tv0 = tid >> 6;
      #pragma unroll
      for (int vv = 0; vv < 64; vv += 4) {
        int v = bvv + vv + tv0;
        Wvt[(size_t)v*HH + bk + tk] = f2bf(tile[tk][vv + tv0] * LOG2E);
      }
    } else if (b < 358) {
      int v = (b - 318)*256 + tid;
      if (v < VP) expbv[v] = (v < VV) ? __expf(bv[v]) : 0.f;
    } else {
      if (tid == 0) out[0] = 0.f;
    }
    return;
  }

  // ================== RNN: block b, groups {2b, 2b+1} ======================
  int n0 = b * 32;                       // 32 samples per block
  int w = tid >> 6, l = tid & 63;
  int l4 = l >> 4, lc = l & 15;

  // persistent Whh B-fragments (shared by both groups)
  short8 bw[2][4];
  int jcol[2];
  #pragma unroll
  for (int c = 0; c < 2; ++c) {
    int jc = (2*w + c)*16 + lc;
    jcol[c] = jc;
    #pragma unroll
    for (int ks = 0; ks < 4; ++ks) {
      const float* p = Whh + (size_t)jc*HH + ks*32 + l4*8;
      bw[c][ks] = cvt2bf8(*(const f32x4*)p, *(const f32x4*)(p+4));
    }
  }

  // H[0] <- h0 for both groups (bf16, swizzled). g0 @ 0, g1 @ 8192.
  {
    int s = tid >> 4, ch = tid & 15;
    int wofs = s*256 + ((ch*16) ^ ((s&7)<<4));
    const float* p0 = h0 + (size_t)(n0 + s)*HH + ch*8;
    *(short8*)(smem + wofs) = cvt2bf8(*(const f32x4*)p0, *(const f32x4*)(p0+4));
    const float* p1 = h0 + (size_t)(n0 + 16 + s)*HH + ch*8;
    *(short8*)(smem + 8192 + wofs) = cvt2bf8(*(const f32x4*)p1, *(const f32x4*)(p1+4));
  }

  // loop-invariant LDS addresses (per group, per buffer)
  const char *rd0_0[4], *rd0_1[4], *rd1_0[4], *rd1_1[4];
  #pragma unroll
  for (int ks = 0; ks < 4; ++ks) {
    int off = lc*256 + ((ks*64 + l4*16) ^ ((lc&7)<<4));
    rd0_0[ks] = smem + off;          rd0_1[ks] = smem + 4096 + off;
    rd1_0[ks] = smem + 8192 + off;   rd1_1[ks] = smem + 12288 + off;
  }
  char *wr0_0[8], *wr0_1[8], *wr1_0[8], *wr1_1[8]; // wrX_B used when reading buf B
  #pragma unroll
  for (int c = 0; c < 2; ++c)
    #pragma unroll
    for (int jj = 0; jj < 4; ++jj) {
      int s = l4*4 + jj;
      int off = s*256 + ((jcol[c]*2) ^ ((s&7)<<4));
      wr0_0[c*4+jj] = smem + 4096 + off;   wr0_1[c*4+jj] = smem + off;
      wr1_0[c*4+jj] = smem + 12288 + off;  wr1_1[c*4+jj] = smem + 8192 + off;
    }
  int fs = tid >> 4, fo = (tid & 15) * 16;
  int fofs = fs*256 + (fo ^ ((fs&7)<<4));
  const char *fr0_0 = smem + fofs,         *fr0_1 = smem + 4096 + fofs;
  const char *fr1_0 = smem + 8192 + fofs,  *fr1_1 = smem + 12288 + fofs;
  unsigned short* hst0 = hsb + (size_t)(n0 + fs)*TT*HH + (fo >> 1) - HH;
  unsigned short* hst1 = hsb + (size_t)(n0 + 16 + fs)*TT*HH + (fo >> 1) - HH;

  // x prefetch: fragment-ordered xbt, per group, per t-parity; depth 2
  const float *xp0_0 = xbt + ((size_t)(2*b)*512 + w*2)*256 + l*4;
  const float *xp0_1 = xp0_0 + 2048;
  const float *xp1_0 = xbt + ((size_t)(2*b+1)*512 + w*2)*256 + l*4;
  const float *xp1_1 = xp1_0 + 2048;
  f32x4 xr0_0_0 = *xp0_0, xr0_0_1 = *(xp0_0 + 256); xp0_0 += 4096;
  f32x4 xr0_1_0 = *xp0_1, xr0_1_1 = *(xp0_1 + 256); xp0_1 += 4096;
  f32x4 xr1_0_0 = *xp1_0, xr1_0_1 = *(xp1_0 + 256); xp1_0 += 4096;
  f32x4 xr1_1_0 = *xp1_1, xr1_1_1 = *(xp1_1 + 256); xp1_1 += 4096;

  lds_barrier();   // H[0] visible (vmcnt prefetches stay in flight)

#define MFMA16(a,b_,c) __builtin_amdgcn_mfma_f32_16x16x32_bf16(a,b_,c,0,0,0)
#define BODY(GI, BUF, DOSTORE) do {                                           \
    short8 ah0 = *(const short8*)rd##GI##_##BUF[0];                           \
    short8 ah1 = *(const short8*)rd##GI##_##BUF[1];                           \
    short8 ah2 = *(const short8*)rd##GI##_##BUF[2];                           \
    short8 ah3 = *(const short8*)rd##GI##_##BUF[3];                           \
    f32x4 xn0 = *(const f32x4*)xp##GI##_##BUF;                                \
    f32x4 xn1 = *(const f32x4*)(xp##GI##_##BUF + 256);                        \
    xp##GI##_##BUF += 4096;                                                   \
    if (DOSTORE) { u32x4 fv = *(const u32x4*)fr##GI##_##BUF;                  \
                   *(u32x4*)hst##GI = fv; }                                   \
    hst##GI += HH;                                                            \
    f32x4 aA0={0.f,0.f,0.f,0.f}, aA1={0.f,0.f,0.f,0.f};                       \
    f32x4 aB0={0.f,0.f,0.f,0.f}, aB1={0.f,0.f,0.f,0.f};                       \
    aA0 = MFMA16(ah0, bw[0][0], aA0); aA1 = MFMA16(ah0, bw[1][0], aA1);       \
    aB0 = MFMA16(ah2, bw[0][2], aB0); aB1 = MFMA16(ah2, bw[1][2], aB1);       \
    aA0 = MFMA16(ah1, bw[0][1], aA0); aA1 = MFMA16(ah1, bw[1][1], aA1);       \
    aB0 = MFMA16(ah3, bw[0][3], aB0); aB1 = MFMA16(ah3, bw[1][3], aB1);       \
    float hv0[4], hv1[4];                                                     \
    _Pragma("unroll")                                                         \
    for (int jj = 0; jj < 4; ++jj) {                                          \
      float v0 = aA0[jj] + aB0[jj] + xr##GI##_##BUF##_0[jj];                  \
      float e0 = __builtin_amdgcn_exp2f(v0 * (2.0f*LOG2E));                   \
      hv0[jj] = fmaf(-2.0f, __builtin_amdgcn_rcpf(e0 + 1.0f), 1.0f);          \
      float v1 = aA1[jj] + aB1[jj] + xr##GI##_##BUF##_1[jj];                  \
      float e1 = __builtin_amdgcn_exp2f(v1 * (2.0f*LOG2E));                   \
      hv1[jj] = fmaf(-2.0f, __builtin_amdgcn_rcpf(e1 + 1.0f), 1.0f);          \
    }                                                                         \
    xr##GI##_##BUF##_0 = xn0; xr##GI##_##BUF##_1 = xn1;                       \
    unsigned int p01 = cvtpk(hv0[0], hv0[1]), p23 = cvtpk(hv0[2], hv0[3]);    \
    unsigned int q01 = cvtpk(hv1[0], hv1[1]), q23 = cvtpk(hv1[2], hv1[3]);    \
    *(unsigned short*)wr##GI##_##BUF[0] = (unsigned short)p01;                \
    *(unsigned short*)wr##GI##_##BUF[1] = (unsigned short)(p01 >> 16);        \
    *(unsigned short*)wr##GI##_##BUF[2] = (unsigned short)p23;                \
    *(unsigned short*)wr##GI##_##BUF[3] = (unsigned short)(p23 >> 16);        \
    *(unsigned short*)wr##GI##_##BUF[4] = (unsigned short)q01;                \
    *(unsigned short*)wr##GI##_##BUF[5] = (unsigned short)(q01 >> 16);        \
    *(unsigned short*)wr##GI##_##BUF[6] = (unsigned short)q23;                \
    *(unsigned short*)wr##GI##_##BUF[7] = (unsigned short)(q23 >> 16);        \
  } while (0)

  BODY(0, 0, 0); BODY(1, 0, 0); lds_barrier();   // t = 0 (no hsb store yet)
  BODY(0, 1, 1); BODY(1, 1, 1); lds_barrier();   // t = 1
  #pragma unroll 1
  for (int it = 1; it < 32; ++it) {
    BODY(0, 0, 1); BODY(1, 0, 1); lds_barrier();
    BODY(0, 1, 1); BODY(1, 1, 1); lds_barrier();
  }
  // final flush: buf0 holds h_64 -> row 63
  { u32x4 fv = *(const u32x4*)fr0_0; *(u32x4*)hst0 = fv; }
  { u32x4 fv = *(const u32x4*)fr1_0; *(u32x4*)hst1 = fv; }
#undef BODY
#undef MFMA16
}

// ---------------------------------------------------------------------------
// K_loss: sum-exp of scores via LDS-staged B, 2-phase pipeline. (unchanged)
// ---------------------------------------------------------------------------
__global__ __launch_bounds__(256) void k_loss(
    const unsigned short* __restrict__ hsb,
    const unsigned short* __restrict__ wvt,
    const float* __restrict__ expbv,
    float* __restrict__ se_part) {
  __shared__ unsigned short bt[2][TILE_BYTES/2];   // 2 x 16 KB
  int tid = threadIdx.x;
  int w = tid >> 6, l = tid & 63;
  int l4 = l >> 4, lc = l & 15;
  int rb = blockIdx.x >> 5;
  int vt = blockIdx.x & 31;
  int wrow = rb*256 + w*64;

  short8 af[4][4];
  #pragma unroll
  for (int sm = 0; sm < 4; ++sm)
    #pragma unroll
    for (int ks = 0; ks < 4; ++ks)
      af[sm][ks] = *(const short8*)(hsb + (size_t)(wrow + sm*16 + lc)*HH + ks*32 + l4*8);

  int T = (lc & 7) << 4;
  int sb[4];
  #pragma unroll
  for (int ks = 0; ks < 4; ++ks) sb[ks] = ((ks*64) + l4*16) ^ T;

#define STAGE(bufi, ct) do {                                                  \
    const char* _gb = (const char*)wvt + (size_t)(ct)*TILE_BYTES;             \
    _Pragma("unroll")                                                         \
    for (int q = 0; q < 4; ++q) {                                             \
      int _off = w*4096 + q*1024 + l*16;                                      \
      int _src = _off ^ (((_off >> 8) & 7) << 4);                             \
      __builtin_amdgcn_global_load_lds(                                       \
        (const __attribute__((address_space(1))) void*)(_gb + _src),          \
        (__attribute__((address_space(3))) void*)((char*)&bt[bufi][0] + w*4096 + q*1024), \
        16, 0, 0);                                                            \
    }                                                                         \
  } while (0)

#define EBLOAD(dst, ct) do {                                                  \
    const float* _e = expbv + (ct)*64 + lc;                                   \
    dst[0] = _e[0]; dst[1] = _e[16]; dst[2] = _e[32]; dst[3] = _e[48];        \
  } while (0)

#define COMPUTE(bufi, ebv_) do {                                              \
    const char* _Bb = (const char*)&bt[bufi][0];                              \
    _Pragma("unroll")                                                         \
    for (int st = 0; st < 4; ++st) {                                          \
      const char* _Bs = _Bb + st*4096 + lc*256;                               \
      short8 _b0 = *(const short8*)(_Bs + sb[0]);                             \
      short8 _b1 = *(const short8*)(_Bs + sb[1]);                             \
      short8 _b2 = *(const short8*)(_Bs + sb[2]);                             \
      short8 _b3 = *(const short8*)(_Bs + sb[3]);                             \
      float _eb = ebv_[st];                                                   \
      _Pragma("unroll")                                                       \
      for (int sm = 0; sm < 4; ++sm) {                                        \
        f32x4 _acc = {0.f,0.f,0.f,0.f};                                       \
        _acc = __builtin_amdgcn_mfma_f32_16x16x32_bf16(af[sm][0], _b0, _acc, 0,0,0); \
        _acc = __builtin_amdgcn_mfma_f32_16x16x32_bf16(af[sm][1], _b1, _acc, 0,0,0); \
        _acc = __builtin_amdgcn_mfma_f32_16x16x32_bf16(af[sm][2], _b2, _acc, 0,0,0); \
        _acc = __builtin_amdgcn_mfma_f32_16x16x32_bf16(af[sm][3], _b3, _acc, 0,0,0); \
        _Pragma("unroll")                                                     \
        for (int jj = 0; jj < 4; ++jj)                                        \
          se[sm][jj] = fmaf(__builtin_amdgcn_exp2f(_acc[jj]), _eb, se[sm][jj]); \
      }                                                                       \
    }                                                                         \
  } while (0)

  float se[4][4] = {{0.f}};
  float ebc[4], ebn[4];
  STAGE(0, vt);
  EBLOAD(ebc, vt);
  __syncthreads();
  int i = 0;
  for (;;) {
    int nextct = vt + (i+1)*VT;
    if (nextct < NTILE) { STAGE((i+1)&1, nextct); EBLOAD(ebn, nextct); }
    COMPUTE(i&1, ebc);
    if (nextct >= NTILE) break;
    __syncthreads();
    ebc[0]=ebn[0]; ebc[1]=ebn[1]; ebc[2]=ebn[2]; ebc[3]=ebn[3];
    ++i;
  }

  #pragma unroll
  for (int sm = 0; sm < 4; ++sm)
    #pragma unroll
    for (int jj = 0; jj < 4; ++jj) {
      float v = se[sm][jj];
      v += __shfl_xor(v, 1); v += __shfl_xor(v, 2);
      v += __shfl_xor(v, 4); v += __shfl_xor(v, 8);
      se[sm][jj] = v;
    }
  if (lc == 0) {
    #pragma unroll
    for (int sm = 0; sm < 4; ++sm)
      #pragma unroll
      for (int jj = 0; jj < 4; ++jj)
        se_part[(size_t)vt*NROW + wrow + sm*16 + l4*4 + jj] = se[sm][jj];
  }
#undef STAGE
#undef EBLOAD
#undef COMPUTE
}

// ---------------------------------------------------------------------------
// K_final: sum 32 partials per row + target score + masked NLL reduction.
// ---------------------------------------------------------------------------
__global__ __launch_bounds__(256) void k_final(
    const unsigned short* __restrict__ hsb,
    const unsigned short* __restrict__ wvt,
    const float* __restrict__ bv,
    const float* __restrict__ se_part,
    const int* __restrict__ captions,
    float* __restrict__ out) {
  int tid = threadIdx.x;
  int w = tid >> 6, l = tid & 63;
  int row = blockIdx.x*32 + w*8 + (l >> 3);
  int seg = l & 7;
  int n = row >> 6, t = row & 63;
  int tg = captions[n*65 + t + 1];
  float sep = 0.f;
  #pragma unroll
  for (int i = 0; i < 4; ++i)
    sep += se_part[(size_t)(seg*4 + i)*NROW + row];
  float part = 0.f;
  if (tg != 0) {
    const unsigned short* a = hsb + (size_t)row*HH + seg*16;
    const unsigned short* bq = wvt + (size_t)tg*HH + seg*16;
    short8 a0 = *(const short8*)a, a1 = *(const short8*)(a+8);
    short8 b0 = *(const short8*)bq, b1 = *(const short8*)(bq+8);
    #pragma unroll
    for (int i = 0; i < 8; ++i) {
      part += bf2f((unsigned short)a0[i]) * bf2f((unsigned short)b0[i]);
      part += bf2f((unsigned short)a1[i]) * bf2f((unsigned short)b1[i]);
    }
  }
  part += __shfl_xor(part, 1); sep += __shfl_xor(sep, 1);
  part += __shfl_xor(part, 2); sep += __shfl_xor(sep, 2);
  part += __shfl_xor(part, 4); sep += __shfl_xor(sep, 4);
  if (seg == 0 && tg != 0) {
    float score = part * LN2 + bv[tg];
    float nll = logf(sep) - score;
    atomicAdd(out, nll * (1.0f/128.0f));
  }
}

extern "C" void kernel_launch(void* const* d_in, const int* in_sizes, int n_in,
                              void* d_out, int out_size, void* d_ws, size_t ws_size,
                              hipStream_t stream) {
  const float* features = (const float*)d_in[0];
  const int*   captions = (const int*)d_in[1];
  const float* W_proj   = (const float*)d_in[2];
  const float* b_proj   = (const float*)d_in[3];
  const float* embed    = (const float*)d_in[4];
  const float* W_ih     = (const float*)d_in[5];
  const float* W_hh     = (const float*)d_in[6];
  const float* b_ih     = (const float*)d_in[7];
  const float* b_hh     = (const float*)d_in[8];
  const float* W_vocab  = (const float*)d_in[9];
  const float* b_vocab  = (const float*)d_in[10];
  float* out = (float*)d_out;
  char* ws = (char*)d_ws;

  float*          h0      = (float*)(ws + 0x000000);            // 64 KB
  float*          se_part = (float*)(ws + 0x010000);            // 1 MB
  unsigned short* hsb     = (unsigned short*)(ws + 0x410000);   // 2 MB
  unsigned short* wvt     = (unsigned short*)(ws + 0x620000);   // 2.57 MB
  float*          expbv   = (float*)(ws + 0x8A0000);            // 40 KB
  float*          xbt     = (float*)(ws + 0x8B0000);            // 4 MB (+slack)

  hipLaunchKernelGGL(k_setup, dim3(160), dim3(256), 0, stream,
                     features, W_proj, b_proj, h0,
                     captions, embed, W_ih, b_ih, b_hh, xbt);
  hipLaunchKernelGGL(k_rnnt, dim3(359), dim3(256), 0, stream,
                     h0, xbt, W_hh, hsb,
                     W_vocab, wvt, b_vocab, expbv, out);
  hipLaunchKernelGGL(k_loss, dim3(32*VT), dim3(256), 0, stream,
                     hsb, wvt, expbv, se_part);
  hipLaunchKernelGGL(k_final, dim3(NROW/32), dim3(256), 0, stream,
                     hsb, wvt, b_vocab, se_part, captions, out);
}

// Round 15
// 95.398 us; speedup vs baseline: 1.2561x; 1.2484x over previous
//
#include <hip/hip_runtime.h>
#include <hip/hip_bf16.h>
#include <math.h>

typedef __attribute__((ext_vector_type(8))) short short8;
typedef __attribute__((ext_vector_type(4))) float f32x4;
typedef __attribute__((ext_vector_type(4))) unsigned int u32x4;
typedef __attribute__((ext_vector_type(2))) unsigned int u32x2;

#define NB   128   // batch
#define TT   64    // timesteps (T-1)
#define DD   512   // feature dim
#define HH   128   // hidden dim
#define WVD  128   // wordvec dim
#define VV   10000 // vocab
#define VP   10048 // vocab padded to multiple of 64
#define NROW (NB*TT)
#define NTILE (VP/64)    // 157 column tiles of 64
#define VT   32          // col-tile streams (blocks per row-block)
#define TILE_BYTES 16384 // 64 cols x 128 k x 2 B
#define LOG2E 1.44269504088896f
#define LN2   0.69314718055995f

__device__ __forceinline__ unsigned short f2bf(float x) {
  union { float f; unsigned int u; } v; v.f = x;
  unsigned int r = v.u + 0x7fffu + ((v.u >> 16) & 1u);
  return (unsigned short)(r >> 16);
}
__device__ __forceinline__ float bf2f(unsigned short u) {
  union { unsigned int i; float f; } v; v.i = ((unsigned int)u) << 16; return v.f;
}
__device__ __forceinline__ short8 cvt2bf8(f32x4 a, f32x4 b) {
  short8 t;
  t[0]=(short)f2bf(a[0]); t[1]=(short)f2bf(a[1]);
  t[2]=(short)f2bf(a[2]); t[3]=(short)f2bf(a[3]);
  t[4]=(short)f2bf(b[0]); t[5]=(short)f2bf(b[1]);
  t[6]=(short)f2bf(b[2]); t[7]=(short)f2bf(b[3]);
  return t;
}
// packed f32 pair -> 2x bf16 in one u32 (RNE), single HW instr on gfx950
__device__ __forceinline__ unsigned int cvtpk(float lo, float hi) {
  unsigned int r;
  asm("v_cvt_pk_bf16_f32 %0, %1, %2" : "=v"(r) : "v"(lo), "v"(hi));
  return r;
}

// LDS-only barrier: lgkmcnt(0) + raw s_barrier; vmcnt stays in flight.
__device__ __forceinline__ void lds_barrier() {
  asm volatile("s_waitcnt lgkmcnt(0)" ::: "memory");
  __builtin_amdgcn_s_barrier();
  asm volatile("" ::: "memory");
  __builtin_amdgcn_sched_barrier(0);
}

// ---------------------------------------------------------------------------
// K_setup: h0 + xbt (everything the RNN needs before it can start).
//   [0,128)   : h0[n] = features[n] @ W_proj + b_proj (VALU GEMV)
//   [128,160) : xbt = gather(embed) @ W_ih^T + b_ih + b_hh via MFMA,
//               scattered into the k_rnn fragment layout:
//               off = (g*512 + t*8 + ct)*256 + (l4r*16+lc)*4 + jjr
// ---------------------------------------------------------------------------
__global__ __launch_bounds__(256) void k_setup(
    const float* __restrict__ features, const float* __restrict__ Wp,
    const float* __restrict__ bp, float* __restrict__ h0,
    const int* __restrict__ captions, const float* __restrict__ embed,
    const float* __restrict__ Wih, const float* __restrict__ bih,
    const float* __restrict__ bhh, float* __restrict__ xbt) {
  __shared__ __align__(16) char smem[32768];
  int b = blockIdx.x, tid = threadIdx.x;

  if (b < 128) {
    int n = b;
    float* fl  = (float*)smem;
    f32x4* red = (f32x4*)(smem + 2048);
    fl[tid]       = features[n*DD + tid];
    fl[tid + 256] = features[n*DD + 256 + tid];
    __syncthreads();
    int jq = (tid & 31) * 4;
    int ks = tid >> 5;
    f32x4 acc = {0.f,0.f,0.f,0.f};
    const float* wp = Wp + (size_t)(ks*64)*HH + jq;
    #pragma unroll 4
    for (int k = 0; k < 64; ++k) {
      f32x4 wv = *(const f32x4*)(wp + (size_t)k*HH);
      acc += fl[ks*64 + k] * wv;
    }
    red[ks*32 + (tid & 31)] = acc;
    __syncthreads();
    if (tid < 32) {
      f32x4 s = red[tid];
      #pragma unroll
      for (int i = 1; i < 8; ++i) s += red[i*32 + tid];
      s += *(const f32x4*)(bp + tid*4);
      *(f32x4*)(h0 + n*HH + tid*4) = s;
    }
  } else {
    // ---- xbt GEMM, scattered into k_rnn fragment layout ----
    char* wihbf = smem;   // 32 KB swizzled bf16 Wih
    int w = tid >> 6, l = tid & 63;
    int l4 = l >> 4, lc = l & 15;
    {
      int row = tid >> 1, half = tid & 1;
      const float* src = Wih + (size_t)row*WVD + half*64;
      #pragma unroll
      for (int i = 0; i < 8; ++i) {
        f32x4 a = *(const f32x4*)(src + i*8);
        f32x4 c = *(const f32x4*)(src + i*8 + 4);
        int chunk = half*8 + i;
        *(short8*)(wihbf + row*256 + ((chunk << 4) ^ ((row & 7) << 4))) = cvt2bf8(a, c);
      }
    }
    int bp2 = b - 128;
    int nn = bp2*4 + w;                 // sample (fixed per wave)
    int g = nn >> 4;
    int sr = nn & 15;
    int l4r = sr >> 2, jjr = sr & 3;
    int lanebase = (l4r*16 + lc)*4 + jjr;
    short8 af[4][4];
    #pragma unroll
    for (int sm = 0; sm < 4; ++sm) {
      int t = sm*16 + lc;
      const float* x = embed + (size_t)captions[nn*65 + t] * WVD;
      #pragma unroll
      for (int ks = 0; ks < 4; ++ks) {
        const float* p = x + ks*32 + l4*8;
        af[sm][ks] = cvt2bf8(*(const f32x4*)p, *(const f32x4*)(p+4));
      }
    }
    __syncthreads();
    #pragma unroll
    for (int ct = 0; ct < 8; ++ct) {
      int rowb = ct*16 + lc;
      short8 bf[4];
      #pragma unroll
      for (int ks = 0; ks < 4; ++ks)
        bf[ks] = *(const short8*)(wihbf + rowb*256 + (((ks*4 + l4) << 4) ^ ((rowb & 7) << 4)));
      int col = ct*16 + lc;
      float bb = bih[col] + bhh[col];
      #pragma unroll
      for (int sm = 0; sm < 4; ++sm) {
        f32x4 acc = {0.f,0.f,0.f,0.f};
        #pragma unroll
        for (int ks = 0; ks < 4; ++ks)
          acc = __builtin_amdgcn_mfma_f32_16x16x32_bf16(af[sm][ks], bf[ks], acc, 0, 0, 0);
        #pragma unroll
        for (int jj = 0; jj < 4; ++jj) {
          int t = sm*16 + l4*4 + jj;
          xbt[(size_t)(g*512 + t*8 + ct)*256 + lanebase] = acc[jj] + bb;
        }
      }
    }
  }
}

// ---------------------------------------------------------------------------
// K_rnnt (512 threads): fused RNN + W_vocab transpose + expbv + out-zero.
//   [0,8)     : MFMA recurrence, 16 samples per block, 8 waves — each wave
//               owns ONE 16-col tile (4 ds_read + 4 MFMA + 8 trans + 4
//               ds_write per step). Depth-2 register prefetch of xbt: the
//               vmcnt wait for step t's x landed at step t-2. lgkm-only
//               barrier; vmcnt never drained in-loop.
//   [8,322)   : Wvt[v][k] = bf16(W_vocab[k][v] * LOG2E) (tile transpose)
//   [322,342) : expbv[v] = exp(b_vocab[v]) (0 for pad)
//   342       : out = 0
// ---------------------------------------------------------------------------
__global__ __launch_bounds__(512) void k_rnnt(
    const float* __restrict__ h0, const float* __restrict__ xbt,
    const float* __restrict__ Whh, unsigned short* __restrict__ hsb,
    const float* __restrict__ Wv, unsigned short* __restrict__ Wvt,
    const float* __restrict__ bv, float* __restrict__ expbv,
    float* __restrict__ out) {
  __shared__ __align__(16) char smem[16640];
  int b = blockIdx.x, tid = threadIdx.x;

  if (b >= 8) {
    if (b < 322) {
      // ---- W_vocab transpose tile (fold LOG2E), 512 threads ----
      float (*tile)[65] = (float (*)[65])smem;
      int tb = b - 8;
      int bvv = (tb >> 1) * 64;
      int bk  = (tb & 1) * 64;
      int tv = tid & 63;
      int tk0 = tid >> 6;                 // 0..7
      #pragma unroll
      for (int kk = 0; kk < 64; kk += 8) {
        int k = bk + kk + tk0;
        int v = bvv + tv;
        tile[kk + tk0][tv] = (v < VV) ? Wv[(size_t)k*VV + v] : 0.f;
      }
      __syncthreads();
      int tk = tid & 63;
      int tv0 = tid >> 6;
      #pragma unroll
      for (int vv = 0; vv < 64; vv += 8) {
        int v = bvv + vv + tv0;
        Wvt[(size_t)v*HH + bk + tk] = f2bf(tile[tk][vv + tv0] * LOG2E);
      }
    } else if (b < 342) {
      int v = (b - 322)*512 + tid;
      if (v < VP) expbv[v] = (v < VV) ? __expf(bv[v]) : 0.f;
    } else {
      if (tid == 0) out[0] = 0.f;
    }
    return;
  }

  // ================== RNN: block b, samples [b*16, b*16+16) ================
  int n0 = b * 16;
  int w = tid >> 6, l = tid & 63;
  int l4 = l >> 4, lc = l & 15;
  int jcol = w*16 + lc;                  // this wave's single col-tile

  // persistent Whh B-fragments (one col-tile per wave)
  short8 bw[4];
  #pragma unroll
  for (int ks = 0; ks < 4; ++ks) {
    const float* p = Whh + (size_t)jcol*HH + ks*32 + l4*8;
    bw[ks] = cvt2bf8(*(const f32x4*)p, *(const f32x4*)(p+4));
  }

  // H[0] <- h0 (bf16, swizzled); threads [0,256) cover it
  if (tid < 256) {
    int s = tid >> 4, ch = tid & 15;
    const float* p = h0 + (size_t)(n0 + s)*HH + ch*8;
    *(short8*)(smem + s*256 + ((ch*16) ^ ((s&7)<<4))) =
        cvt2bf8(*(const f32x4*)p, *(const f32x4*)(p + 4));
  }

  // loop-invariant LDS addresses
  const char *rd0[4], *rd1[4];
  #pragma unroll
  for (int ks = 0; ks < 4; ++ks) {
    int off = lc*256 + ((ks*64 + l4*16) ^ ((lc&7)<<4));
    rd0[ks] = smem + off;
    rd1[ks] = smem + 4096 + off;
  }
  char *wr0[4], *wr1[4];   // wr0 used when reading buf0 (writes buf1)
  #pragma unroll
  for (int jj = 0; jj < 4; ++jj) {
    int s = l4*4 + jj;
    int off = s*256 + ((jcol*2) ^ ((s&7)<<4));
    wr0[jj] = smem + 4096 + off;
    wr1[jj] = smem + off;
  }
  int fs = tid >> 5, fo = (tid & 31) * 8;       // 8B per thread, 512 thr
  const char* fr0 = smem + fs*256 + (fo ^ ((fs&7)<<4));
  const char* fr1 = fr0 + 4096;
  unsigned short* hst = hsb + (size_t)(n0 + fs)*TT*HH + (fo >> 1) - HH;

  // x prefetch: fragment-ordered xbt; per parity keep {xcur, xpend}.
  // Wave w reads f32x4 at float offset (b*512 + t*8 + w)*256 + l*4.
  const float* xpE = xbt + ((size_t)b*512 + w)*256 + l*4;     // t=0
  const float* xpO = xpE + 2048;                              // t=1
  f32x4 xcE = *(const f32x4*)xpE;            // t=0
  f32x4 xpendE = *(const f32x4*)(xpE + 4096);// t=2
  xpE += 8192;                               // next issue: t=4
  f32x4 xcO = *(const f32x4*)xpO;            // t=1
  f32x4 xpendO = *(const f32x4*)(xpO + 4096);// t=3
  xpO += 8192;                               // next issue: t=5

  lds_barrier();   // H[0] visible (vmcnt prefetches stay in flight)

#define MFMA16(a,b_,c) __builtin_amdgcn_mfma_f32_16x16x32_bf16(a,b_,c,0,0,0)
#define BODY(BUF, XC, XPEND, XP, DOSTORE) do {                                \
    short8 ah0 = *(const short8*)rd##BUF[0];                                  \
    short8 ah1 = *(const short8*)rd##BUF[1];                                  \
    short8 ah2 = *(const short8*)rd##BUF[2];                                  \
    short8 ah3 = *(const short8*)rd##BUF[3];                                  \
    if (DOSTORE) { u32x2 fv = *(const u32x2*)fr##BUF; *(u32x2*)hst = fv; }    \
    hst += HH;                                                                \
    f32x4 aA = {0.f,0.f,0.f,0.f}, aB = {0.f,0.f,0.f,0.f};                     \
    aA = MFMA16(ah0, bw[0], aA);                                              \
    aB = MFMA16(ah2, bw[2], aB);                                              \
    aA = MFMA16(ah1, bw[1], aA);                                              \
    aB = MFMA16(ah3, bw[3], aB);                                              \
    float hv[4];                                                              \
    _Pragma("unroll")                                                         \
    for (int jj = 0; jj < 4; ++jj) {                                          \
      float v = aA[jj] + aB[jj] + XC[jj];                                     \
      float e = __builtin_amdgcn_exp2f(v * (2.0f*LOG2E));                     \
      hv[jj] = fmaf(-2.0f, __builtin_amdgcn_rcpf(e + 1.0f), 1.0f);            \
    }                                                                         \
    XC = XPEND;                 /* waits for load issued 2 steps ago */       \
    XPEND = *(const f32x4*)XP;  /* in flight until t+2 */                     \
    XP += 2048;                 /* +2 t-steps (floats) */                     \
    unsigned int p01 = cvtpk(hv[0], hv[1]), p23 = cvtpk(hv[2], hv[3]);        \
    *(unsigned short*)wr##BUF[0] = (unsigned short)p01;                       \
    *(unsigned short*)wr##BUF[1] = (unsigned short)(p01 >> 16);               \
    *(unsigned short*)wr##BUF[2] = (unsigned short)p23;                       \
    *(unsigned short*)wr##BUF[3] = (unsigned short)(p23 >> 16);               \
    lds_barrier();                                                            \
  } while (0)

  BODY(0, xcE, xpendE, xpE, 0);          // t = 0 (no hsb store yet)
  BODY(1, xcO, xpendO, xpO, 1);          // t = 1
  #pragma unroll 1
  for (int it = 1; it < 32; ++it) {
    BODY(0, xcE, xpendE, xpE, 1);
    BODY(1, xcO, xpendO, xpO, 1);
  }
  // final flush: buf0 holds h_64 -> row 63
  { u32x2 fv = *(const u32x2*)fr0; *(u32x2*)hst = fv; }
#undef BODY
#undef MFMA16
}

// ---------------------------------------------------------------------------
// K_loss: sum-exp of scores via LDS-staged B, 2-phase pipeline. (unchanged)
// ---------------------------------------------------------------------------
__global__ __launch_bounds__(256) void k_loss(
    const unsigned short* __restrict__ hsb,
    const unsigned short* __restrict__ wvt,
    const float* __restrict__ expbv,
    float* __restrict__ se_part) {
  __shared__ unsigned short bt[2][TILE_BYTES/2];   // 2 x 16 KB
  int tid = threadIdx.x;
  int w = tid >> 6, l = tid & 63;
  int l4 = l >> 4, lc = l & 15;
  int rb = blockIdx.x >> 5;
  int vt = blockIdx.x & 31;
  int wrow = rb*256 + w*64;

  short8 af[4][4];
  #pragma unroll
  for (int sm = 0; sm < 4; ++sm)
    #pragma unroll
    for (int ks = 0; ks < 4; ++ks)
      af[sm][ks] = *(const short8*)(hsb + (size_t)(wrow + sm*16 + lc)*HH + ks*32 + l4*8);

  int T = (lc & 7) << 4;
  int sb[4];
  #pragma unroll
  for (int ks = 0; ks < 4; ++ks) sb[ks] = ((ks*64) + l4*16) ^ T;

#define STAGE(bufi, ct) do {                                                  \
    const char* _gb = (const char*)wvt + (size_t)(ct)*TILE_BYTES;             \
    _Pragma("unroll")                                                         \
    for (int q = 0; q < 4; ++q) {                                             \
      int _off = w*4096 + q*1024 + l*16;                                      \
      int _src = _off ^ (((_off >> 8) & 7) << 4);                             \
      __builtin_amdgcn_global_load_lds(                                       \
        (const __attribute__((address_space(1))) void*)(_gb + _src),          \
        (__attribute__((address_space(3))) void*)((char*)&bt[bufi][0] + w*4096 + q*1024), \
        16, 0, 0);                                                            \
    }                                                                         \
  } while (0)

#define EBLOAD(dst, ct) do {                                                  \
    const float* _e = expbv + (ct)*64 + lc;                                   \
    dst[0] = _e[0]; dst[1] = _e[16]; dst[2] = _e[32]; dst[3] = _e[48];        \
  } while (0)

#define COMPUTE(bufi, ebv_) do {                                              \
    const char* _Bb = (const char*)&bt[bufi][0];                              \
    _Pragma("unroll")                                                         \
    for (int st = 0; st < 4; ++st) {                                          \
      const char* _Bs = _Bb + st*4096 + lc*256;                               \
      short8 _b0 = *(const short8*)(_Bs + sb[0]);                             \
      short8 _b1 = *(const short8*)(_Bs + sb[1]);                             \
      short8 _b2 = *(const short8*)(_Bs + sb[2]);                             \
      short8 _b3 = *(const short8*)(_Bs + sb[3]);                             \
      float _eb = ebv_[st];                                                   \
      _Pragma("unroll")                                                       \
      for (int sm = 0; sm < 4; ++sm) {                                        \
        f32x4 _acc = {0.f,0.f,0.f,0.f};                                       \
        _acc = __builtin_amdgcn_mfma_f32_16x16x32_bf16(af[sm][0], _b0, _acc, 0,0,0); \
        _acc = __builtin_amdgcn_mfma_f32_16x16x32_bf16(af[sm][1], _b1, _acc, 0,0,0); \
        _acc = __builtin_amdgcn_mfma_f32_16x16x32_bf16(af[sm][2], _b2, _acc, 0,0,0); \
        _acc = __builtin_amdgcn_mfma_f32_16x16x32_bf16(af[sm][3], _b3, _acc, 0,0,0); \
        _Pragma("unroll")                                                     \
        for (int jj = 0; jj < 4; ++jj)                                        \
          se[sm][jj] = fmaf(__builtin_amdgcn_exp2f(_acc[jj]), _eb, se[sm][jj]); \
      }                                                                       \
    }                                                                         \
  } while (0)

  float se[4][4] = {{0.f}};
  float ebc[4], ebn[4];
  STAGE(0, vt);
  EBLOAD(ebc, vt);
  __syncthreads();
  int i = 0;
  for (;;) {
    int nextct = vt + (i+1)*VT;
    if (nextct < NTILE) { STAGE((i+1)&1, nextct); EBLOAD(ebn, nextct); }
    COMPUTE(i&1, ebc);
    if (nextct >= NTILE) break;
    __syncthreads();
    ebc[0]=ebn[0]; ebc[1]=ebn[1]; ebc[2]=ebn[2]; ebc[3]=ebn[3];
    ++i;
  }

  #pragma unroll
  for (int sm = 0; sm < 4; ++sm)
    #pragma unroll
    for (int jj = 0; jj < 4; ++jj) {
      float v = se[sm][jj];
      v += __shfl_xor(v, 1); v += __shfl_xor(v, 2);
      v += __shfl_xor(v, 4); v += __shfl_xor(v, 8);
      se[sm][jj] = v;
    }
  if (lc == 0) {
    #pragma unroll
    for (int sm = 0; sm < 4; ++sm)
      #pragma unroll
      for (int jj = 0; jj < 4; ++jj)
        se_part[(size_t)vt*NROW + wrow + sm*16 + l4*4 + jj] = se[sm][jj];
  }
#undef STAGE
#undef EBLOAD
#undef COMPUTE
}

// ---------------------------------------------------------------------------
// K_final: sum 32 partials per row + target score + masked NLL reduction.
// ---------------------------------------------------------------------------
__global__ __launch_bounds__(256) void k_final(
    const unsigned short* __restrict__ hsb,
    const unsigned short* __restrict__ wvt,
    const float* __restrict__ bv,
    const float* __restrict__ se_part,
    const int* __restrict__ captions,
    float* __restrict__ out) {
  int tid = threadIdx.x;
  int w = tid >> 6, l = tid & 63;
  int row = blockIdx.x*32 + w*8 + (l >> 3);
  int seg = l & 7;
  int n = row >> 6, t = row & 63;
  int tg = captions[n*65 + t + 1];
  float sep = 0.f;
  #pragma unroll
  for (int i = 0; i < 4; ++i)
    sep += se_part[(size_t)(seg*4 + i)*NROW + row];
  float part = 0.f;
  if (tg != 0) {
    const unsigned short* a = hsb + (size_t)row*HH + seg*16;
    const unsigned short* bq = wvt + (size_t)tg*HH + seg*16;
    short8 a0 = *(const short8*)a, a1 = *(const short8*)(a+8);
    short8 b0 = *(const short8*)bq, b1 = *(const short8*)(bq+8);
    #pragma unroll
    for (int i = 0; i < 8; ++i) {
      part += bf2f((unsigned short)a0[i]) * bf2f((unsigned short)b0[i]);
      part += bf2f((unsigned short)a1[i]) * bf2f((unsigned short)b1[i]);
    }
  }
  part += __shfl_xor(part, 1); sep += __shfl_xor(sep, 1);
  part += __shfl_xor(part, 2); sep += __shfl_xor(sep, 2);
  part += __shfl_xor(part, 4); sep += __shfl_xor(sep, 4);
  if (seg == 0 && tg != 0) {
    float score = part * LN2 + bv[tg];
    float nll = logf(sep) - score;
    atomicAdd(out, nll * (1.0f/128.0f));
  }
}

extern "C" void kernel_launch(void* const* d_in, const int* in_sizes, int n_in,
                              void* d_out, int out_size, void* d_ws, size_t ws_size,
                              hipStream_t stream) {
  const float* features = (const float*)d_in[0];
  const int*   captions = (const int*)d_in[1];
  const float* W_proj   = (const float*)d_in[2];
  const float* b_proj   = (const float*)d_in[3];
  const float* embed    = (const float*)d_in[4];
  const float* W_ih     = (const float*)d_in[5];
  const float* W_hh     = (const float*)d_in[6];
  const float* b_ih     = (const float*)d_in[7];
  const float* b_hh     = (const float*)d_in[8];
  const float* W_vocab  = (const float*)d_in[9];
  const float* b_vocab  = (const float*)d_in[10];
  float* out = (float*)d_out;
  char* ws = (char*)d_ws;

  float*          h0      = (float*)(ws + 0x000000);            // 64 KB
  float*          se_part = (float*)(ws + 0x010000);            // 1 MB
  unsigned short* hsb     = (unsigned short*)(ws + 0x410000);   // 2 MB
  unsigned short* wvt     = (unsigned short*)(ws + 0x620000);   // 2.57 MB
  float*          expbv   = (float*)(ws + 0x8A0000);            // 40 KB
  float*          xbt     = (float*)(ws + 0x8B0000);            // 4 MB (+slack)

  hipLaunchKernelGGL(k_setup, dim3(160), dim3(256), 0, stream,
                     features, W_proj, b_proj, h0,
                     captions, embed, W_ih, b_ih, b_hh, xbt);
  hipLaunchKernelGGL(k_rnnt, dim3(343), dim3(512), 0, stream,
                     h0, xbt, W_hh, hsb,
                     W_vocab, wvt, b_vocab, expbv, out);
  hipLaunchKernelGGL(k_loss, dim3(32*VT), dim3(256), 0, stream,
                     hsb, wvt, expbv, se_part);
  hipLaunchKernelGGL(k_final, dim3(NROW/32), dim3(256), 0, stream,
                     hsb, wvt, b_vocab, se_part, captions, out);
}

// Round 16
// 91.874 us; speedup vs baseline: 1.3042x; 1.0383x over previous
//
#include <hip/hip_runtime.h>
#include <hip/hip_bf16.h>
#include <math.h>

typedef __attribute__((ext_vector_type(8))) short short8;
typedef __attribute__((ext_vector_type(4))) float f32x4;
typedef __attribute__((ext_vector_type(4))) unsigned int u32x4;
typedef __attribute__((ext_vector_type(2))) unsigned int u32x2;

#define NB   128   // batch
#define TT   64    // timesteps (T-1)
#define DD   512   // feature dim
#define HH   128   // hidden dim
#define WVD  128   // wordvec dim
#define VV   10000 // vocab
#define VP   10048 // vocab padded to multiple of 64
#define NROW (NB*TT)
#define NTILE (VP/64)    // 157 column tiles of 64
#define VT   32          // col-tile streams (blocks per row-block)
#define TILE_BYTES 16384 // 64 cols x 128 k x 2 B
#define LOG2E 1.44269504088896f
#define LN2   0.69314718055995f

__device__ __forceinline__ unsigned short f2bf(float x) {
  union { float f; unsigned int u; } v; v.f = x;
  unsigned int r = v.u + 0x7fffu + ((v.u >> 16) & 1u);
  return (unsigned short)(r >> 16);
}
__device__ __forceinline__ float bf2f(unsigned short u) {
  union { unsigned int i; float f; } v; v.i = ((unsigned int)u) << 16; return v.f;
}
__device__ __forceinline__ short8 cvt2bf8(f32x4 a, f32x4 b) {
  short8 t;
  t[0]=(short)f2bf(a[0]); t[1]=(short)f2bf(a[1]);
  t[2]=(short)f2bf(a[2]); t[3]=(short)f2bf(a[3]);
  t[4]=(short)f2bf(b[0]); t[5]=(short)f2bf(b[1]);
  t[6]=(short)f2bf(b[2]); t[7]=(short)f2bf(b[3]);
  return t;
}
// packed f32 pair -> 2x bf16 in one u32 (RNE), single HW instr on gfx950
__device__ __forceinline__ unsigned int cvtpk(float lo, float hi) {
  unsigned int r;
  asm("v_cvt_pk_bf16_f32 %0, %1, %2" : "=v"(r) : "v"(lo), "v"(hi));
  return r;
}

// LDS-only barrier: lgkmcnt(0) + raw s_barrier; vmcnt stays in flight.
__device__ __forceinline__ void lds_barrier() {
  asm volatile("s_waitcnt lgkmcnt(0)" ::: "memory");
  __builtin_amdgcn_s_barrier();
  asm volatile("" ::: "memory");
  __builtin_amdgcn_sched_barrier(0);
}

// ---------------------------------------------------------------------------
// K_setup: h0 + xbt (everything the RNN needs before it can start).
//   [0,128)   : h0[n] = features[n] @ W_proj + b_proj (VALU GEMV)
//   [128,160) : xbt = gather(embed) @ W_ih^T + b_ih + b_hh via MFMA,
//               scattered into the k_rnn fragment layout:
//               off = (g*512 + t*8 + ct)*256 + (l4r*16+lc)*4 + jjr
// ---------------------------------------------------------------------------
__global__ __launch_bounds__(256) void k_setup(
    const float* __restrict__ features, const float* __restrict__ Wp,
    const float* __restrict__ bp, float* __restrict__ h0,
    const int* __restrict__ captions, const float* __restrict__ embed,
    const float* __restrict__ Wih, const float* __restrict__ bih,
    const float* __restrict__ bhh, float* __restrict__ xbt) {
  __shared__ __align__(16) char smem[32768];
  int b = blockIdx.x, tid = threadIdx.x;

  if (b < 128) {
    int n = b;
    float* fl  = (float*)smem;
    f32x4* red = (f32x4*)(smem + 2048);
    fl[tid]       = features[n*DD + tid];
    fl[tid + 256] = features[n*DD + 256 + tid];
    __syncthreads();
    int jq = (tid & 31) * 4;
    int ks = tid >> 5;
    f32x4 acc = {0.f,0.f,0.f,0.f};
    const float* wp = Wp + (size_t)(ks*64)*HH + jq;
    #pragma unroll 4
    for (int k = 0; k < 64; ++k) {
      f32x4 wv = *(const f32x4*)(wp + (size_t)k*HH);
      acc += fl[ks*64 + k] * wv;
    }
    red[ks*32 + (tid & 31)] = acc;
    __syncthreads();
    if (tid < 32) {
      f32x4 s = red[tid];
      #pragma unroll
      for (int i = 1; i < 8; ++i) s += red[i*32 + tid];
      s += *(const f32x4*)(bp + tid*4);
      *(f32x4*)(h0 + n*HH + tid*4) = s;
    }
  } else {
    // ---- xbt GEMM, scattered into k_rnn fragment layout ----
    char* wihbf = smem;   // 32 KB swizzled bf16 Wih
    int w = tid >> 6, l = tid & 63;
    int l4 = l >> 4, lc = l & 15;
    {
      int row = tid >> 1, half = tid & 1;
      const float* src = Wih + (size_t)row*WVD + half*64;
      #pragma unroll
      for (int i = 0; i < 8; ++i) {
        f32x4 a = *(const f32x4*)(src + i*8);
        f32x4 c = *(const f32x4*)(src + i*8 + 4);
        int chunk = half*8 + i;
        *(short8*)(wihbf + row*256 + ((chunk << 4) ^ ((row & 7) << 4))) = cvt2bf8(a, c);
      }
    }
    int bp2 = b - 128;
    int nn = bp2*4 + w;                 // sample (fixed per wave)
    int g = nn >> 4;
    int sr = nn & 15;
    int l4r = sr >> 2, jjr = sr & 3;
    int lanebase = (l4r*16 + lc)*4 + jjr;
    short8 af[4][4];
    #pragma unroll
    for (int sm = 0; sm < 4; ++sm) {
      int t = sm*16 + lc;
      const float* x = embed + (size_t)captions[nn*65 + t] * WVD;
      #pragma unroll
      for (int ks = 0; ks < 4; ++ks) {
        const float* p = x + ks*32 + l4*8;
        af[sm][ks] = cvt2bf8(*(const f32x4*)p, *(const f32x4*)(p+4));
      }
    }
    __syncthreads();
    #pragma unroll
    for (int ct = 0; ct < 8; ++ct) {
      int rowb = ct*16 + lc;
      short8 bf[4];
      #pragma unroll
      for (int ks = 0; ks < 4; ++ks)
        bf[ks] = *(const short8*)(wihbf + rowb*256 + (((ks*4 + l4) << 4) ^ ((rowb & 7) << 4)));
      int col = ct*16 + lc;
      float bb = bih[col] + bhh[col];
      #pragma unroll
      for (int sm = 0; sm < 4; ++sm) {
        f32x4 acc = {0.f,0.f,0.f,0.f};
        #pragma unroll
        for (int ks = 0; ks < 4; ++ks)
          acc = __builtin_amdgcn_mfma_f32_16x16x32_bf16(af[sm][ks], bf[ks], acc, 0, 0, 0);
        #pragma unroll
        for (int jj = 0; jj < 4; ++jj) {
          int t = sm*16 + l4*4 + jj;
          xbt[(size_t)(g*512 + t*8 + ct)*256 + lanebase] = acc[jj] + bb;
        }
      }
    }
  }
}

// ---------------------------------------------------------------------------
// K_rnnt (512 threads): fused RNN + W_vocab transpose + expbv + out-zero.
//   [0,8)     : MFMA recurrence, 16 samples per block, 8 waves — each wave
//               owns ONE 16-col tile (4 ds_read + 4 MFMA + 8 trans + 4
//               ds_write per step). Depth-2 register prefetch of xbt: the
//               vmcnt wait for step t's x landed at step t-2. lgkm-only
//               barrier; vmcnt never drained in-loop.
//   [8,322)   : Wvt[v][k] = bf16(W_vocab[k][v] * LOG2E) (tile transpose)
//   [322,342) : expbv[v] = exp(b_vocab[v]) (0 for pad)
//   342       : out = 0
// ---------------------------------------------------------------------------
__global__ __launch_bounds__(512) void k_rnnt(
    const float* __restrict__ h0, const float* __restrict__ xbt,
    const float* __restrict__ Whh, unsigned short* __restrict__ hsb,
    const float* __restrict__ Wv, unsigned short* __restrict__ Wvt,
    const float* __restrict__ bv, float* __restrict__ expbv,
    float* __restrict__ out) {
  __shared__ __align__(16) char smem[16640];
  int b = blockIdx.x, tid = threadIdx.x;

  if (b >= 8) {
    if (b < 322) {
      // ---- W_vocab transpose tile (fold LOG2E), 512 threads ----
      float (*tile)[65] = (float (*)[65])smem;
      int tb = b - 8;
      int bvv = (tb >> 1) * 64;
      int bk  = (tb & 1) * 64;
      int tv = tid & 63;
      int tk0 = tid >> 6;                 // 0..7
      #pragma unroll
      for (int kk = 0; kk < 64; kk += 8) {
        int k = bk + kk + tk0;
        int v = bvv + tv;
        tile[kk + tk0][tv] = (v < VV) ? Wv[(size_t)k*VV + v] : 0.f;
      }
      __syncthreads();
      int tk = tid & 63;
      int tv0 = tid >> 6;
      #pragma unroll
      for (int vv = 0; vv < 64; vv += 8) {
        int v = bvv + vv + tv0;
        Wvt[(size_t)v*HH + bk + tk] = f2bf(tile[tk][vv + tv0] * LOG2E);
      }
    } else if (b < 342) {
      int v = (b - 322)*512 + tid;
      if (v < VP) expbv[v] = (v < VV) ? __expf(bv[v]) : 0.f;
    } else {
      if (tid == 0) out[0] = 0.f;
    }
    return;
  }

  // ================== RNN: block b, samples [b*16, b*16+16) ================
  int n0 = b * 16;
  int w = tid >> 6, l = tid & 63;
  int l4 = l >> 4, lc = l & 15;
  int jcol = w*16 + lc;                  // this wave's single col-tile

  // persistent Whh B-fragments (one col-tile per wave)
  short8 bw[4];
  #pragma unroll
  for (int ks = 0; ks < 4; ++ks) {
    const float* p = Whh + (size_t)jcol*HH + ks*32 + l4*8;
    bw[ks] = cvt2bf8(*(const f32x4*)p, *(const f32x4*)(p+4));
  }

  // H[0] <- h0 (bf16, swizzled); threads [0,256) cover it
  if (tid < 256) {
    int s = tid >> 4, ch = tid & 15;
    const float* p = h0 + (size_t)(n0 + s)*HH + ch*8;
    *(short8*)(smem + s*256 + ((ch*16) ^ ((s&7)<<4))) =
        cvt2bf8(*(const f32x4*)p, *(const f32x4*)(p + 4));
  }

  // loop-invariant LDS addresses
  const char *rd0[4], *rd1[4];
  #pragma unroll
  for (int ks = 0; ks < 4; ++ks) {
    int off = lc*256 + ((ks*64 + l4*16) ^ ((lc&7)<<4));
    rd0[ks] = smem + off;
    rd1[ks] = smem + 4096 + off;
  }
  char *wr0[4], *wr1[4];   // wr0 used when reading buf0 (writes buf1)
  #pragma unroll
  for (int jj = 0; jj < 4; ++jj) {
    int s = l4*4 + jj;
    int off = s*256 + ((jcol*2) ^ ((s&7)<<4));
    wr0[jj] = smem + 4096 + off;
    wr1[jj] = smem + off;
  }
  int fs = tid >> 5, fo = (tid & 31) * 8;       // 8B per thread, 512 thr
  const char* fr0 = smem + fs*256 + (fo ^ ((fs&7)<<4));
  const char* fr1 = fr0 + 4096;
  unsigned short* hst = hsb + (size_t)(n0 + fs)*TT*HH + (fo >> 1) - HH;

  // x prefetch: fragment-ordered xbt; per parity keep {xcur, xpend}.
  // Wave w reads f32x4 at float offset (b*512 + t*8 + w)*256 + l*4.
  const float* xpE = xbt + ((size_t)b*512 + w)*256 + l*4;     // t=0
  const float* xpO = xpE + 2048;                              // t=1
  f32x4 xcE = *(const f32x4*)xpE;            // t=0
  f32x4 xpendE = *(const f32x4*)(xpE + 4096);// t=2
  xpE += 8192;                               // next issue: t=4
  f32x4 xcO = *(const f32x4*)xpO;            // t=1
  f32x4 xpendO = *(const f32x4*)(xpO + 4096);// t=3
  xpO += 8192;                               // next issue: t=5

  lds_barrier();   // H[0] visible (vmcnt prefetches stay in flight)

#define MFMA16(a,b_,c) __builtin_amdgcn_mfma_f32_16x16x32_bf16(a,b_,c,0,0,0)
#define BODY(BUF, XC, XPEND, XP, DOSTORE) do {                                \
    short8 ah0 = *(const short8*)rd##BUF[0];                                  \
    short8 ah1 = *(const short8*)rd##BUF[1];                                  \
    short8 ah2 = *(const short8*)rd##BUF[2];                                  \
    short8 ah3 = *(const short8*)rd##BUF[3];                                  \
    if (DOSTORE) { u32x2 fv = *(const u32x2*)fr##BUF; *(u32x2*)hst = fv; }    \
    hst += HH;                                                                \
    f32x4 aA = {0.f,0.f,0.f,0.f}, aB = {0.f,0.f,0.f,0.f};                     \
    aA = MFMA16(ah0, bw[0], aA);                                              \
    aB = MFMA16(ah2, bw[2], aB);                                              \
    aA = MFMA16(ah1, bw[1], aA);                                              \
    aB = MFMA16(ah3, bw[3], aB);                                              \
    float hv[4];                                                              \
    _Pragma("unroll")                                                         \
    for (int jj = 0; jj < 4; ++jj) {                                          \
      float v = aA[jj] + aB[jj] + XC[jj];                                     \
      float e = __builtin_amdgcn_exp2f(v * (2.0f*LOG2E));                     \
      hv[jj] = fmaf(-2.0f, __builtin_amdgcn_rcpf(e + 1.0f), 1.0f);            \
    }                                                                         \
    XC = XPEND;                 /* waits for load issued 2 steps ago */       \
    XPEND = *(const f32x4*)XP;  /* in flight until t+2 */                     \
    XP += 2048;                 /* +2 t-steps (floats) */                     \
    unsigned int p01 = cvtpk(hv[0], hv[1]), p23 = cvtpk(hv[2], hv[3]);        \
    *(unsigned short*)wr##BUF[0] = (unsigned short)p01;                       \
    *(unsigned short*)wr##BUF[1] = (unsigned short)(p01 >> 16);               \
    *(unsigned short*)wr##BUF[2] = (unsigned short)p23;                       \
    *(unsigned short*)wr##BUF[3] = (unsigned short)(p23 >> 16);               \
    lds_barrier();                                                            \
  } while (0)

  BODY(0, xcE, xpendE, xpE, 0);          // t = 0 (no hsb store yet)
  BODY(1, xcO, xpendO, xpO, 1);          // t = 1
  #pragma unroll 1
  for (int it = 1; it < 32; ++it) {
    BODY(0, xcE, xpendE, xpE, 1);
    BODY(1, xcO, xpendO, xpO, 1);
  }
  // final flush: buf0 holds h_64 -> row 63
  { u32x2 fv = *(const u32x2*)fr0; *(u32x2*)hst = fv; }
#undef BODY
#undef MFMA16
}

// ---------------------------------------------------------------------------
// K_loss: sum-exp of scores via LDS-staged B, 2-phase pipeline. (unchanged)
// ---------------------------------------------------------------------------
__global__ __launch_bounds__(256) void k_loss(
    const unsigned short* __restrict__ hsb,
    const unsigned short* __restrict__ wvt,
    const float* __restrict__ expbv,
    float* __restrict__ se_part) {
  __shared__ unsigned short bt[2][TILE_BYTES/2];   // 2 x 16 KB
  int tid = threadIdx.x;
  int w = tid >> 6, l = tid & 63;
  int l4 = l >> 4, lc = l & 15;
  int rb = blockIdx.x >> 5;
  int vt = blockIdx.x & 31;
  int wrow = rb*256 + w*64;

  short8 af[4][4];
  #pragma unroll
  for (int sm = 0; sm < 4; ++sm)
    #pragma unroll
    for (int ks = 0; ks < 4; ++ks)
      af[sm][ks] = *(const short8*)(hsb + (size_t)(wrow + sm*16 + lc)*HH + ks*32 + l4*8);

  int T = (lc & 7) << 4;
  int sb[4];
  #pragma unroll
  for (int ks = 0; ks < 4; ++ks) sb[ks] = ((ks*64) + l4*16) ^ T;

#define STAGE(bufi, ct) do {                                                  \
    const char* _gb = (const char*)wvt + (size_t)(ct)*TILE_BYTES;             \
    _Pragma("unroll")                                                         \
    for (int q = 0; q < 4; ++q) {                                             \
      int _off = w*4096 + q*1024 + l*16;                                      \
      int _src = _off ^ (((_off >> 8) & 7) << 4);                             \
      __builtin_amdgcn_global_load_lds(                                       \
        (const __attribute__((address_space(1))) void*)(_gb + _src),          \
        (__attribute__((address_space(3))) void*)((char*)&bt[bufi][0] + w*4096 + q*1024), \
        16, 0, 0);                                                            \
    }                                                                         \
  } while (0)

#define EBLOAD(dst, ct) do {                                                  \
    const float* _e = expbv + (ct)*64 + lc;                                   \
    dst[0] = _e[0]; dst[1] = _e[16]; dst[2] = _e[32]; dst[3] = _e[48];        \
  } while (0)

#define COMPUTE(bufi, ebv_) do {                                              \
    const char* _Bb = (const char*)&bt[bufi][0];                              \
    _Pragma("unroll")                                                         \
    for (int st = 0; st < 4; ++st) {                                          \
      const char* _Bs = _Bb + st*4096 + lc*256;                               \
      short8 _b0 = *(const short8*)(_Bs + sb[0]);                             \
      short8 _b1 = *(const short8*)(_Bs + sb[1]);                             \
      short8 _b2 = *(const short8*)(_Bs + sb[2]);                             \
      short8 _b3 = *(const short8*)(_Bs + sb[3]);                             \
      float _eb = ebv_[st];                                                   \
      _Pragma("unroll")                                                       \
      for (int sm = 0; sm < 4; ++sm) {                                        \
        f32x4 _acc = {0.f,0.f,0.f,0.f};                                       \
        _acc = __builtin_amdgcn_mfma_f32_16x16x32_bf16(af[sm][0], _b0, _acc, 0,0,0); \
        _acc = __builtin_amdgcn_mfma_f32_16x16x32_bf16(af[sm][1], _b1, _acc, 0,0,0); \
        _acc = __builtin_amdgcn_mfma_f32_16x16x32_bf16(af[sm][2], _b2, _acc, 0,0,0); \
        _acc = __builtin_amdgcn_mfma_f32_16x16x32_bf16(af[sm][3], _b3, _acc, 0,0,0); \
        _Pragma("unroll")                                                     \
        for (int jj = 0; jj < 4; ++jj)                                        \
          se[sm][jj] = fmaf(__builtin_amdgcn_exp2f(_acc[jj]), _eb, se[sm][jj]); \
      }                                                                       \
    }                                                                         \
  } while (0)

  float se[4][4] = {{0.f}};
  float ebc[4], ebn[4];
  STAGE(0, vt);
  EBLOAD(ebc, vt);
  __syncthreads();
  int i = 0;
  for (;;) {
    int nextct = vt + (i+1)*VT;
    if (nextct < NTILE) { STAGE((i+1)&1, nextct); EBLOAD(ebn, nextct); }
    COMPUTE(i&1, ebc);
    if (nextct >= NTILE) break;
    __syncthreads();
    ebc[0]=ebn[0]; ebc[1]=ebn[1]; ebc[2]=ebn[2]; ebc[3]=ebn[3];
    ++i;
  }

  #pragma unroll
  for (int sm = 0; sm < 4; ++sm)
    #pragma unroll
    for (int jj = 0; jj < 4; ++jj) {
      float v = se[sm][jj];
      v += __shfl_xor(v, 1); v += __shfl_xor(v, 2);
      v += __shfl_xor(v, 4); v += __shfl_xor(v, 8);
      se[sm][jj] = v;
    }
  if (lc == 0) {
    #pragma unroll
    for (int sm = 0; sm < 4; ++sm)
      #pragma unroll
      for (int jj = 0; jj < 4; ++jj)
        se_part[(size_t)vt*NROW + wrow + sm*16 + l4*4 + jj] = se[sm][jj];
  }
#undef STAGE
#undef EBLOAD
#undef COMPUTE
}

// ---------------------------------------------------------------------------
// K_final: sum 32 partials per row + target score + masked NLL reduction.
// ---------------------------------------------------------------------------
__global__ __launch_bounds__(256) void k_final(
    const unsigned short* __restrict__ hsb,
    const unsigned short* __restrict__ wvt,
    const float* __restrict__ bv,
    const float* __restrict__ se_part,
    const int* __restrict__ captions,
    float* __restrict__ out) {
  int tid = threadIdx.x;
  int w = tid >> 6, l = tid & 63;
  int row = blockIdx.x*32 + w*8 + (l >> 3);
  int seg = l & 7;
  int n = row >> 6, t = row & 63;
  int tg = captions[n*65 + t + 1];
  float sep = 0.f;
  #pragma unroll
  for (int i = 0; i < 4; ++i)
    sep += se_part[(size_t)(seg*4 + i)*NROW + row];
  float part = 0.f;
  if (tg != 0) {
    const unsigned short* a = hsb + (size_t)row*HH + seg*16;
    const unsigned short* bq = wvt + (size_t)tg*HH + seg*16;
    short8 a0 = *(const short8*)a, a1 = *(const short8*)(a+8);
    short8 b0 = *(const short8*)bq, b1 = *(const short8*)(bq+8);
    #pragma unroll
    for (int i = 0; i < 8; ++i) {
      part += bf2f((unsigned short)a0[i]) * bf2f((unsigned short)b0[i]);
      part += bf2f((unsigned short)a1[i]) * bf2f((unsigned short)b1[i]);
    }
  }
  part += __shfl_xor(part, 1); sep += __shfl_xor(sep, 1);
  part += __shfl_xor(part, 2); sep += __shfl_xor(sep, 2);
  part += __shfl_xor(part, 4); sep += __shfl_xor(sep, 4);
  if (seg == 0 && tg != 0) {
    float score = part * LN2 + bv[tg];
    float nll = logf(sep) - score;
    atomicAdd(out, nll * (1.0f/128.0f));
  }
}

extern "C" void kernel_launch(void* const* d_in, const int* in_sizes, int n_in,
                              void* d_out, int out_size, void* d_ws, size_t ws_size,
                              hipStream_t stream) {
  const float* features = (const float*)d_in[0];
  const int*   captions = (const int*)d_in[1];
  const float* W_proj   = (const float*)d_in[2];
  const float* b_proj   = (const float*)d_in[3];
  const float* embed    = (const float*)d_in[4];
  const float* W_ih     = (const float*)d_in[5];
  const float* W_hh     = (const float*)d_in[6];
  const float* b_ih     = (const float*)d_in[7];
  const float* b_hh     = (const float*)d_in[8];
  const float* W_vocab  = (const float*)d_in[9];
  const float* b_vocab  = (const float*)d_in[10];
  float* out = (float*)d_out;
  char* ws = (char*)d_ws;

  float*          h0      = (float*)(ws + 0x000000);            // 64 KB
  float*          se_part = (float*)(ws + 0x010000);            // 1 MB
  unsigned short* hsb     = (unsigned short*)(ws + 0x410000);   // 2 MB
  unsigned short* wvt     = (unsigned short*)(ws + 0x620000);   // 2.57 MB
  float*          expbv   = (float*)(ws + 0x8A0000);            // 40 KB
  float*          xbt     = (float*)(ws + 0x8B0000);            // 4 MB (+slack)

  hipLaunchKernelGGL(k_setup, dim3(160), dim3(256), 0, stream,
                     features, W_proj, b_proj, h0,
                     captions, embed, W_ih, b_ih, b_hh, xbt);
  hipLaunchKernelGGL(k_rnnt, dim3(343), dim3(512), 0, stream,
                     h0, xbt, W_hh, hsb,
                     W_vocab, wvt, b_vocab, expbv, out);
  hipLaunchKernelGGL(k_loss, dim3(32*VT), dim3(256), 0, stream,
                     hsb, wvt, expbv, se_part);
  hipLaunchKernelGGL(k_final, dim3(NROW/32), dim3(256), 0, stream,
                     hsb, wvt, b_vocab, se_part, captions, out);
}